// Round 15
// baseline (603.029 us; speedup 1.0000x reference)
//
#include <hip/hip_runtime.h>

namespace {

constexpr int kN  = 32;
constexpr int kC  = 512;
constexpr int kH  = 32;
constexpr int kW  = 32;
constexpr int kHW = kH * kW;

// bf16 chunked-padded activation layout: [n][chunk=ci/32][34 rows][34 cols][32 ci]
constexpr int PCH   = 36992;                 // 34*34*32 elems per (n,chunk) plane
constexpr size_t WTF_ELEMS = (size_t)9 * kC * kC;          // 2,359,296 bf16
constexpr size_t XH_ELEMS  = (size_t)kN * 16 * PCH;        // 18,939,904 bf16
constexpr size_t QKV_ELEMS = (size_t)kN * kHW * kC;        // 16,777,216 bf16

using bf16x8 = __attribute__((ext_vector_type(8))) short;
using bf16x4 = __attribute__((ext_vector_type(4))) short;
using f32x4  = __attribute__((ext_vector_type(4))) float;

__device__ __forceinline__ float bf2f(short s) {
  unsigned u = ((unsigned)(unsigned short)s) << 16;
  return __builtin_bit_cast(float, u);
}
__device__ __forceinline__ short f2bf(float f) {
  unsigned u = __builtin_bit_cast(unsigned, f);
  u += 0x7FFFu + ((u >> 16) & 1u);
  return (short)(u >> 16);
}
__device__ __forceinline__ void gload_lds16(const void* g, void* l) {
  __builtin_amdgcn_global_load_lds(
      (const __attribute__((address_space(1))) void*)g,
      (__attribute__((address_space(3))) void*)l, 16, 0, 0);
}

// ---- weight pack (all 4 tensors, z selects): w[co][ci][3][3] f32 ->
//      wtf[t][kk][nnG][lane][8] bf16 ----
__global__ __launch_bounds__(256) void wtf_pack_kernel(
    const float* __restrict__ wq, const float* __restrict__ wk,
    const float* __restrict__ wv, const float* __restrict__ wo,
    short* __restrict__ oq, short* __restrict__ ok,
    short* __restrict__ ov, short* __restrict__ oo) {
  const float* wsrc[4] = {wq, wk, wv, wo};
  short* wdst[4] = {oq, ok, ov, oo};
  const float* w = wsrc[blockIdx.z];
  short* wtf = wdst[blockIdx.z];
  __shared__ float tile[32][289];  // [co][ci*9+t]
  const int co0 = blockIdx.x * 32;
  const int ci0 = blockIdx.y * 32;
  for (int idx = threadIdx.x; idx < 32 * 288; idx += 256) {
    int c = idx % 288, r = idx / 288;
    tile[r][c] = w[(size_t)(co0 + r) * (kC * 9) + (size_t)ci0 * 9 + c];
  }
  __syncthreads();
  const int kkb  = ci0 >> 5;
  const int nnG0 = co0 >> 4;
  for (int g = threadIdx.x; g < 9 * 2 * 64; g += 256) {
    int laneg = g & 63;
    int nnL   = (g >> 6) & 1;
    int t     = g >> 7;  // 0..8
    int hi    = laneg >> 4;
    int coL   = nnL * 16 + (laneg & 15);
    bf16x8 pk;
#pragma unroll
    for (int j = 0; j < 8; ++j) pk[j] = f2bf(tile[coL][(hi * 8 + j) * 9 + t]);
    *(bf16x8*)&wtf[(((size_t)t * 16 + kkb) * 32 + nnG0 + nnL) * 512 + laneg * 8] = pk;
  }
}

// ---- x NCHW f32 -> xh chunked-padded bf16 ---------------------------------
__global__ __launch_bounds__(256) void x2xh_kernel(
    const float* __restrict__ x, short* __restrict__ xh) {
  __shared__ float tile[32][33];  // [w][ci]
  const int ch = blockIdx.x;   // 0..15
  const int h  = blockIdx.y;   // 0..31
  const int n  = blockIdx.z;   // 0..31
  const int w0 = threadIdx.x & 31;
  const int c0 = threadIdx.x >> 5;
#pragma unroll
  for (int pass = 0; pass < 4; ++pass) {
    int cir = pass * 8 + c0;
    tile[w0][cir] = x[(((size_t)n * kC + ch * 32 + cir) * kH + h) * kW + w0];
  }
  __syncthreads();
  const int wv = threadIdx.x >> 3;
  const int g4 = (threadIdx.x & 7) * 4;
  bf16x4 pk;
#pragma unroll
  for (int j = 0; j < 4; ++j) pk[j] = f2bf(tile[wv][g4 + j]);
  *(bf16x4*)&xh[(((size_t)n * 16 + ch) * 1156 + (size_t)(h + 1) * 34 + (wv + 1)) * 32 + g4] = pk;
}

// ---- halo zeroing for xh and vh (rows 0/33, cols 0/33 of each plane) ------
__global__ __launch_bounds__(256) void halo_zero_kernel(
    short* __restrict__ xh, short* __restrict__ vh) {
  short* base = (blockIdx.x & 1) ? vh : xh;
  const int plane = blockIdx.x >> 1;  // 0..511 = n*16+ch
  short* dst = base + (size_t)plane * PCH;
  const int t = threadIdx.x;
  if (t < 132) {
    int row, col;
    if (t < 34)       { row = 0;          col = t; }
    else if (t < 68)  { row = 33;         col = t - 34; }
    else if (t < 100) { row = t - 68 + 1; col = 0; }
    else              { row = t - 100 + 1; col = 33; }
    const bf16x8 z = {0, 0, 0, 0, 0, 0, 0, 0};
    short* q = dst + (size_t)(row * 34 + col) * 32;
#pragma unroll
    for (int j = 0; j < 4; ++j) *(bf16x8*)&q[j * 8] = z;
  }
}

// ---- FUSED q/k/v conv3x3 via MFMA implicit shift-GEMM ---------------------
// 64sp x 64co blocks (grid 4096): acc[3][4] = 48 AGPR + ~65 arch <= 128 ->
// 4 waves/SIMD. Each wave owns a distinct 16-co quarter x all 64 sp (no
// intra-block B duplication). co slowest in-XCD (B L2-resident, R8/R12).
__global__ __launch_bounds__(256, 4) void conv_qkv_kernel(
    const short* __restrict__ xin,
    const short* __restrict__ wtq, const short* __restrict__ wtk,
    const short* __restrict__ wtv,
    short* __restrict__ outq, short* __restrict__ outk,
    short* __restrict__ outv) {
  __shared__ __align__(16) short As[3][6144];  // 4 rows x 34 pos x 32 ci (padded to 12KB)
  const int tid  = threadIdx.x;
  const int lane = tid & 63;
  const int l15  = lane & 15, lhi = lane >> 4;
  const int w    = tid >> 6;       // wave 0..3 = co quarter
  const int wbase = tid & 192;

  // 4096 blocks. xcd = bid&7; m = bid>>3 in 0..511:
  //   spt = m&15 (fastest), n = xcd*4 + ((m>>4)&3), co-tile = m>>6 (slowest).
  const int xcd = blockIdx.x & 7;
  const int m   = blockIdx.x >> 3;
  const int spt = m & 15;
  const int n   = xcd * 4 + ((m >> 4) & 3);
  const int co0 = (m >> 6) * 64;
  const int sp0 = spt * 64;

  const short* srcA = xin + (size_t)n * (16 * PCH) + (size_t)(spt * 2) * (34 * 32);
  const size_t boff = ((size_t)(co0 >> 4) + w) * 512 + lane * 8;
  const short* bp[3] = {wtq + boff, wtk + boff, wtv + boff};

  f32x4 acc[3][4];
#pragma unroll
  for (int c = 0; c < 3; ++c)
#pragma unroll
    for (int mf = 0; mf < 4; ++mf)
#pragma unroll
      for (int r = 0; r < 4; ++r) acc[c][mf][r] = 0.f;

  // slab = 8704B; stage 3 passes x 4096B (overshoot reads land in-bounds of
  // ws; LDS positions >= 136 rows never read by a-frags)
#define STAGE_A(kk, buf)                                                      \
  {                                                                           \
    const short* gA = srcA + (size_t)(kk) * PCH;                              \
    _Pragma("unroll") for (int pass = 0; pass < 3; ++pass)                    \
        gload_lds16(gA + (size_t)(pass * 256 + tid) * 8,                      \
                    &As[buf][(pass * 256 + wbase) * 8]);                      \
  }

  STAGE_A(0, 0);
  STAGE_A(1, 1);
  bf16x8 cur[3], nxt[3];
#pragma unroll
  for (int j = 0; j < 3; ++j)  // b(kk=0, t=0): issued AFTER the two stages
    cur[j] = *(const bf16x8*)&bp[j][0];

  int ab = 0;   // buffer holding stage kk
  int sb = 2;   // buffer to stage kk+2 into
  for (int kk = 0; kk < 16; ++kk) {
    // FIFO oldest-first: vmcnt(6) = stage(kk+1) 3 + last tap's 3 B-prefetches
    asm volatile("s_waitcnt vmcnt(6)" ::: "memory");
    __builtin_amdgcn_s_barrier();
#pragma unroll
    for (int t = 0; t < 9; ++t) {
      {  // prefetch next tap's B (t==8: next kk's tap 0; harmless tail read)
        const int nt  = (t < 8) ? (t + 1) : 0;
        const int nkk = (t < 8) ? kk : kk + 1;
        const size_t bo = (size_t)(nt * 16 + nkk) * 16384;
#pragma unroll
        for (int j = 0; j < 3; ++j)
          nxt[j] = *(const bf16x8*)&bp[j][bo];
      }
      if (t == 1 && kk < 14) STAGE_A(kk + 2, sb);
      const int dy = t / 3, dx = t % 3;
      bf16x8 a[4];
#pragma unroll
      for (int mf = 0; mf < 4; ++mf) {
        const int pb = ((mf >> 1) + dy) * 34 + (mf & 1) * 16 + l15 + dx;
        a[mf] = *(const bf16x8*)&As[ab][pb * 32 + lhi * 8];
      }
      __builtin_amdgcn_s_setprio(1);
#pragma unroll
      for (int c = 0; c < 3; ++c)
#pragma unroll
        for (int mf = 0; mf < 4; ++mf)
          acc[c][mf] = __builtin_amdgcn_mfma_f32_16x16x32_bf16(
              a[mf], cur[c], acc[c][mf], 0, 0, 0);
      __builtin_amdgcn_s_setprio(0);
#pragma unroll
      for (int j = 0; j < 3; ++j) cur[j] = nxt[j];
    }
    ab = (ab == 2) ? 0 : ab + 1;
    sb = (sb == 2) ? 0 : sb + 1;
  }
#undef STAGE_A

  short* outs[3] = {outq, outk, outv};
#pragma unroll
  for (int c = 0; c < 3; ++c) {
    short* out = outs[c];
#pragma unroll
    for (int mf = 0; mf < 4; ++mf)
#pragma unroll
      for (int r = 0; r < 4; ++r) {
        size_t off = ((size_t)n * kHW + sp0 + mf * 16 + lhi * 4 + r) * kC
                     + co0 + w * 16 + l15;
        out[off] = f2bf(acc[c][mf][r]);
      }
  }
}

// ---- conv_o (single conv, 128x128 tile), R12/R14-measured (frozen) --------
__global__ __launch_bounds__(256, 3) void conv_o_kernel(
    const short* __restrict__ xin, const short* __restrict__ wtf,
    const float* __restrict__ xres, float* __restrict__ out) {
  __shared__ __align__(16) short As[3][8192];
  const int tid  = threadIdx.x;
  const int lane = tid & 63;
  const int l15  = lane & 15, lhi = lane >> 4;
  const int wv   = tid >> 6;
  const int wm   = wv >> 1, wn = wv & 1;
  const int wbase = tid & 192;

  const int xcd = blockIdx.x & 7;
  const int m   = blockIdx.x >> 3;
  const int co0 = (m >> 5) * 128;
  const int spt = m & 7;
  const int n   = xcd * 4 + ((m >> 3) & 3);
  const int h0  = spt * 4;
  const int sp0 = spt * 128;

  const short* srcA = xin + (size_t)n * (16 * PCH) + (size_t)h0 * (34 * 32);
  const short* bptr = wtf + ((size_t)(co0 >> 4) + wn * 4) * 512 + lane * 8;

  f32x4 acc[4][4];
#pragma unroll
  for (int mf = 0; mf < 4; ++mf)
#pragma unroll
    for (int nf = 0; nf < 4; ++nf)
#pragma unroll
      for (int r = 0; r < 4; ++r) acc[mf][nf][r] = 0.f;

#define STAGE_A(kk, buf)                                                      \
  {                                                                           \
    const short* gA = srcA + (size_t)(kk) * PCH;                              \
    _Pragma("unroll") for (int pass = 0; pass < 4; ++pass)                    \
        gload_lds16(gA + (size_t)(pass * 256 + tid) * 8,                      \
                    &As[buf][(pass * 256 + wbase) * 8]);                      \
  }

  STAGE_A(0, 0);
  STAGE_A(1, 1);
  bf16x8 cur[4], nxt[4];
#pragma unroll
  for (int j = 0; j < 4; ++j)
    cur[j] = *(const bf16x8*)&bptr[(size_t)j * 512];

  int ab = 0, sb = 2;
  for (int kk = 0; kk < 16; ++kk) {
    asm volatile("s_waitcnt vmcnt(8)" ::: "memory");
    __builtin_amdgcn_s_barrier();
#pragma unroll
    for (int t = 0; t < 9; ++t) {
      {
        const int nt  = (t < 8) ? (t + 1) : 0;
        const int nkk = (t < 8) ? kk : kk + 1;
        const size_t bo = (size_t)(nt * 16 + nkk) * 16384;
#pragma unroll
        for (int j = 0; j < 4; ++j)
          nxt[j] = *(const bf16x8*)&bptr[bo + (size_t)j * 512];
      }
      if (t == 1 && kk < 14) STAGE_A(kk + 2, sb);
      const int dy = t / 3, dx = t % 3;
      bf16x8 a[4];
#pragma unroll
      for (int mf = 0; mf < 4; ++mf) {
        const int pb = (wm * 2 + (mf >> 1) + dy) * 34 + (mf & 1) * 16 + l15 + dx;
        a[mf] = *(const bf16x8*)&As[ab][pb * 32 + lhi * 8];
      }
      __builtin_amdgcn_s_setprio(1);
#pragma unroll
      for (int mf = 0; mf < 4; ++mf)
#pragma unroll
        for (int nf = 0; nf < 4; ++nf)
          acc[mf][nf] = __builtin_amdgcn_mfma_f32_16x16x32_bf16(
              a[mf], cur[nf], acc[mf][nf], 0, 0, 0);
      __builtin_amdgcn_s_setprio(0);
#pragma unroll
      for (int j = 0; j < 4; ++j) cur[j] = nxt[j];
    }
    ab = (ab == 2) ? 0 : ab + 1;
    sb = (sb == 2) ? 0 : sb + 1;
  }
#undef STAGE_A

  float* T = (float*)&As[0][0];
#pragma unroll
  for (int nf = 0; nf < 4; ++nf) {
    __syncthreads();
    const int coL = wn * 16 + l15;
#pragma unroll
    for (int mf = 0; mf < 4; ++mf)
#pragma unroll
      for (int r = 0; r < 4; ++r)
        T[coL * 129 + wm * 64 + mf * 16 + lhi * 4 + r] = acc[mf][nf][r];
    __syncthreads();
#pragma unroll
    for (int it = 0; it < 16; ++it) {
      int idx = it * 256 + tid;
      int c = idx >> 7, sp = idx & 127;
      int co = co0 + (c >> 4) * 64 + nf * 16 + (c & 15);
      size_t off = ((size_t)n * kC + co) * kHW + sp0 + sp;
      out[off] = T[c * 129 + sp] + xres[off];
    }
  }
}

// ---- MFMA per-pixel attention + fused GN partial sums (R14-verified) ------
__global__ __launch_bounds__(256) void attn_mfma_kernel(
    const short* q, const short* __restrict__ k,
    const short* __restrict__ v, short* virt, float* __restrict__ gsum) {
  __shared__ __align__(16) short Qs[32 * 72];  // [i][c 64 + pad 8]
  __shared__ __align__(16) short Ks[32 * 72];  // [j][c 64 + pad 8]
  __shared__ __align__(16) float Ps[32 * 36];  // [i][j 32 + pad 4]
  __shared__ __align__(16) short Vt[64 * 40];  // [cL][j 32 + pad 8], swizzled
  const int p    = blockIdx.x;
  const int tid  = threadIdx.x;
  const int lane = tid & 63;
  const int l15  = lane & 15, lhi = lane >> 4;
  const int w    = tid >> 6;       // wave 0..3
  const int iq   = w >> 1, jq = w & 1;  // S quadrant

  f32x4 accS = {0.f, 0.f, 0.f, 0.f};
  const int si = tid >> 3;
  const int sc = (tid & 7) * 8;
  for (int c0 = 0; c0 < kC; c0 += 64) {
    __syncthreads();
    {
      size_t g = ((size_t)si * kHW + p) * kC + c0 + sc;
      *(bf16x8*)&Qs[si * 72 + sc] = *(const bf16x8*)&q[g];
      *(bf16x8*)&Ks[si * 72 + sc] = *(const bf16x8*)&k[g];
    }
    __syncthreads();
#pragma unroll
    for (int cs = 0; cs < 2; ++cs) {
      bf16x8 aq = *(const bf16x8*)&Qs[(iq * 16 + l15) * 72 + cs * 32 + lhi * 8];
      bf16x8 bk = *(const bf16x8*)&Ks[(jq * 16 + l15) * 72 + cs * 32 + lhi * 8];
      accS = __builtin_amdgcn_mfma_f32_16x16x32_bf16(aq, bk, accS, 0, 0, 0);
    }
  }
  __syncthreads();
  constexpr float scale = 0.044194173824159216f;  // 1/sqrt(512)
#pragma unroll
  for (int r = 0; r < 4; ++r)
    Ps[(iq * 16 + lhi * 4 + r) * 36 + jq * 16 + l15] = accS[r] * scale;
  __syncthreads();

  {
    const int i  = tid >> 3;
    const int j0 = (tid & 7) * 4;
    float a0 = Ps[i * 36 + j0], a1 = Ps[i * 36 + j0 + 1];
    float a2 = Ps[i * 36 + j0 + 2], a3 = Ps[i * 36 + j0 + 3];
    float mx = fmaxf(fmaxf(a0, a1), fmaxf(a2, a3));
    for (int off = 1; off < 8; off <<= 1) mx = fmaxf(mx, __shfl_xor(mx, off));
    float e0 = __expf(a0 - mx), e1 = __expf(a1 - mx);
    float e2 = __expf(a2 - mx), e3 = __expf(a3 - mx);
    float s = e0 + e1 + e2 + e3;
    for (int off = 1; off < 8; off <<= 1) s += __shfl_xor(s, off);
    const float inv = 1.f / s;
    Ps[i * 36 + j0]     = e0 * inv;
    Ps[i * 36 + j0 + 1] = e1 * inv;
    Ps[i * 36 + j0 + 2] = e2 * inv;
    Ps[i * 36 + j0 + 3] = e3 * inv;
  }
  __syncthreads();

  bf16x8 ap[2];
#pragma unroll
  for (int it = 0; it < 2; ++it) {
    const float* pr = &Ps[(it * 16 + l15) * 36 + lhi * 8];
    float4 lo = *(const float4*)pr;
    float4 hi4 = *(const float4*)(pr + 4);
    ap[it][0] = f2bf(lo.x);  ap[it][1] = f2bf(lo.y);
    ap[it][2] = f2bf(lo.z);  ap[it][3] = f2bf(lo.w);
    ap[it][4] = f2bf(hi4.x); ap[it][5] = f2bf(hi4.y);
    ap[it][6] = f2bf(hi4.z); ap[it][7] = f2bf(hi4.w);
  }
  __syncthreads();  // all reads of Ps done before epilogue reuses it

  float gs[8], gq2[8];
#pragma unroll
  for (int idx = 0; idx < 8; ++idx) { gs[idx] = 0.f; gq2[idx] = 0.f; }

  const f32x4 zacc = {0.f, 0.f, 0.f, 0.f};
  for (int c0 = 0; c0 < kC; c0 += 64) {
    __syncthreads();
    {
      const int j = tid >> 3, c8g = tid & 7;
      bf16x8 vvv = *(const bf16x8*)&v[((size_t)j * kHW + p) * kC + c0 + c8g * 8];
#pragma unroll
      for (int jj = 0; jj < 8; ++jj) {
        int c = c8g * 8 + jj;
        int byte = (c * 80 + j * 2) ^ (((c >> 3) & 7) << 4);
        *(short*)((char*)Vt + byte) = vvv[jj];
      }
    }
    __syncthreads();
    {
      const int c = w * 16 + l15;
      const int byte = (c * 80 + lhi * 16) ^ (((c >> 3) & 7) << 4);
      bf16x8 bv = *(const bf16x8*)((const char*)Vt + byte);
#pragma unroll
      for (int it = 0; it < 2; ++it) {
        f32x4 o = __builtin_amdgcn_mfma_f32_16x16x32_bf16(ap[it], bv, zacc, 0, 0, 0);
#pragma unroll
        for (int r = 0; r < 4; ++r) {
          short ob = f2bf(o[r]);
          virt[((size_t)(it * 16 + lhi * 4 + r) * kHW + p) * kC + c0 + w * 16 + l15] = ob;
          float fv = bf2f(ob);
          gs[it * 4 + r] += fv;
          gq2[it * 4 + r] = fmaf(fv, fv, gq2[it * 4 + r]);
        }
      }
    }
  }

  // GN partial sums: reduce over the 16 l15-lanes sharing (it,lhi,r)
#pragma unroll
  for (int idx = 0; idx < 8; ++idx)
    for (int off = 1; off < 16; off <<= 1) {
      gs[idx]  += __shfl_xor(gs[idx], off);
      gq2[idx] += __shfl_xor(gq2[idx], off);
    }
  __syncthreads();  // Vt reads done; Ps reuse below
  float* SS = Ps;   // [w][32 inst][2] = 256 floats
  if (l15 == 0) {
#pragma unroll
    for (int idx = 0; idx < 8; ++idx) {
      int it = idx >> 2, r = idx & 3;
      int i = it * 16 + lhi * 4 + r;
      SS[(w * 32 + i) * 2]     = gs[idx];
      SS[(w * 32 + i) * 2 + 1] = gq2[idx];
    }
  }
  __syncthreads();
  if (tid < 32) {
    float s = 0.f, q2 = 0.f;
#pragma unroll
    for (int ww = 0; ww < 4; ++ww) {
      s  += SS[(ww * 32 + tid) * 2];
      q2 += SS[(ww * 32 + tid) * 2 + 1];
    }
    atomicAdd(&gsum[tid], s);
    atomicAdd(&gsum[32 + tid], q2);
  }
}

// ---- GN finalize from fused sums ------------------------------------------
__global__ __launch_bounds__(64) void gn_final_kernel(
    const float* __restrict__ gsum, float* __restrict__ stats) {
  if (threadIdx.x < 32) {
    constexpr float invn = 1.f / ((float)kHW * kC);
    float mean = gsum[threadIdx.x] * invn;
    float var = gsum[32 + threadIdx.x] * invn - mean * mean;
    stats[threadIdx.x] = mean;
    stats[32 + threadIdx.x] = rsqrtf(var + 1e-5f);
  }
}

// ---- GN apply + affine + ReLU -> chunked-padded bf16 ----------------------
__global__ __launch_bounds__(256) void gn_apply_kernel(
    const short* __restrict__ virt, const float* __restrict__ stats,
    const float* __restrict__ gamma, const float* __restrict__ beta,
    short* __restrict__ vh) {
  const size_t g = (size_t)blockIdx.x * 256 + threadIdx.x;
  const int i    = (int)(g >> 16);
  const int rest = (int)(g & 65535);
  const int p    = rest >> 6;
  const int c8g  = rest & 63;
  const int ci   = c8g * 8;
  const float mean = stats[i];
  const float rstd = stats[32 + i];
  bf16x8 vv = *(const bf16x8*)&virt[((size_t)i * kHW + p) * kC + ci];
  const float4 ga = ((const float4*)gamma)[c8g * 2];
  const float4 gb = ((const float4*)gamma)[c8g * 2 + 1];
  const float4 ba = ((const float4*)beta)[c8g * 2];
  const float4 bb = ((const float4*)beta)[c8g * 2 + 1];
  const float gv[8] = {ga.x, ga.y, ga.z, ga.w, gb.x, gb.y, gb.z, gb.w};
  const float bv[8] = {ba.x, ba.y, ba.z, ba.w, bb.x, bb.y, bb.z, bb.w};
  bf16x8 o;
#pragma unroll
  for (int jj = 0; jj < 8; ++jj) {
    float f = (bf2f(vv[jj]) - mean) * rstd;
    f = fmaxf(fmaf(f, gv[jj], bv[jj]), 0.f);
    o[jj] = f2bf(f);
  }
  const size_t dst =
      (((size_t)i * 16 + (ci >> 5)) * 1156 + (size_t)((p >> 5) + 1) * 34 + (p & 31) + 1) * 32
      + (ci & 31);
  *(bf16x8*)&vh[dst] = o;
}

}  // namespace

extern "C" void kernel_launch(void* const* d_in, const int* in_sizes, int n_in,
                              void* d_out, int out_size, void* d_ws,
                              size_t ws_size, hipStream_t stream) {
  const float* x     = (const float*)d_in[0];
  const float* w_q   = (const float*)d_in[1];
  const float* w_k   = (const float*)d_in[2];
  const float* w_v   = (const float*)d_in[3];
  const float* w_o   = (const float*)d_in[4];
  const float* gamma = (const float*)d_in[5];
  const float* beta  = (const float*)d_in[6];

  short* ws    = (short*)d_ws;
  short* wtf_q = ws;
  short* wtf_k = wtf_q + WTF_ELEMS;
  short* wtf_v = wtf_k + WTF_ELEMS;
  short* wtf_o = wtf_v + WTF_ELEMS;
  short* xh    = wtf_o + WTF_ELEMS;
  short* vh    = xh + XH_ELEMS;
  short* qb    = vh + XH_ELEMS;
  short* kb    = qb + QKV_ELEMS;
  short* vb    = kb + QKV_ELEMS;
  float* stats = (float*)(vb + QKV_ELEMS);  // 64 floats
  float* gsum  = stats + 64;                // 64 floats (sum, sumsq)
  short* virt  = qb;  // attn writes per-position after reading q
  // zero halos (rows/cols 0 & 33 of each padded plane) + fused-GN accumulators
  halo_zero_kernel<<<1024, 256, 0, stream>>>(xh, vh);
  hipMemsetAsync(gsum, 0, 64 * sizeof(float), stream);

  wtf_pack_kernel<<<dim3(16, 16, 4), 256, 0, stream>>>(
      w_q, w_k, w_v, w_o, wtf_q, wtf_k, wtf_v, wtf_o);

  x2xh_kernel<<<dim3(16, 32, 32), 256, 0, stream>>>(x, xh);

  conv_qkv_kernel<<<4096, 256, 0, stream>>>(xh, wtf_q, wtf_k, wtf_v,
                                            qb, kb, vb);

  attn_mfma_kernel<<<kHW, 256, 0, stream>>>(qb, kb, vb, virt, gsum);

  gn_final_kernel<<<1, 64, 0, stream>>>(gsum, stats);
  gn_apply_kernel<<<(int)(QKV_ELEMS / 8 / 256), 256, 0, stream>>>(
      virt, stats, gamma, beta, vh);

  conv_o_kernel<<<1024, 256, 0, stream>>>(vh, wtf_o, x, (float*)d_out);
}

// Round 16
// 553.291 us; speedup vs baseline: 1.0899x; 1.0899x over previous
//
#include <hip/hip_runtime.h>

namespace {

constexpr int kN  = 32;
constexpr int kC  = 512;
constexpr int kH  = 32;
constexpr int kW  = 32;
constexpr int kHW = kH * kW;

// bf16 chunked-padded activation layout: [n][chunk=ci/32][34 rows][34 cols][32 ci]
constexpr int PCH   = 36992;                 // 34*34*32 elems per (n,chunk) plane
constexpr size_t WTF_ELEMS = (size_t)9 * kC * kC;          // 2,359,296 bf16
constexpr size_t XH_ELEMS  = (size_t)kN * 16 * PCH;        // 18,939,904 bf16
constexpr size_t QKV_ELEMS = (size_t)kN * kHW * kC;        // 16,777,216 bf16

using bf16x8 = __attribute__((ext_vector_type(8))) short;
using bf16x4 = __attribute__((ext_vector_type(4))) short;
using f32x4  = __attribute__((ext_vector_type(4))) float;

__device__ __forceinline__ float bf2f(short s) {
  unsigned u = ((unsigned)(unsigned short)s) << 16;
  return __builtin_bit_cast(float, u);
}
__device__ __forceinline__ short f2bf(float f) {
  unsigned u = __builtin_bit_cast(unsigned, f);
  u += 0x7FFFu + ((u >> 16) & 1u);
  return (short)(u >> 16);
}
__device__ __forceinline__ void gload_lds16(const void* g, void* l) {
  __builtin_amdgcn_global_load_lds(
      (const __attribute__((address_space(1))) void*)g,
      (__attribute__((address_space(3))) void*)l, 16, 0, 0);
}

// ---- weight pack (all 4 tensors, z selects): w[co][ci][3][3] f32 ->
//      wtf[t][kk][nnG][lane][8] bf16 ----
__global__ __launch_bounds__(256) void wtf_pack_kernel(
    const float* __restrict__ wq, const float* __restrict__ wk,
    const float* __restrict__ wv, const float* __restrict__ wo,
    short* __restrict__ oq, short* __restrict__ ok,
    short* __restrict__ ov, short* __restrict__ oo) {
  const float* wsrc[4] = {wq, wk, wv, wo};
  short* wdst[4] = {oq, ok, ov, oo};
  const float* w = wsrc[blockIdx.z];
  short* wtf = wdst[blockIdx.z];
  __shared__ float tile[32][289];  // [co][ci*9+t]
  const int co0 = blockIdx.x * 32;
  const int ci0 = blockIdx.y * 32;
  for (int idx = threadIdx.x; idx < 32 * 288; idx += 256) {
    int c = idx % 288, r = idx / 288;
    tile[r][c] = w[(size_t)(co0 + r) * (kC * 9) + (size_t)ci0 * 9 + c];
  }
  __syncthreads();
  const int kkb  = ci0 >> 5;
  const int nnG0 = co0 >> 4;
  for (int g = threadIdx.x; g < 9 * 2 * 64; g += 256) {
    int laneg = g & 63;
    int nnL   = (g >> 6) & 1;
    int t     = g >> 7;  // 0..8
    int hi    = laneg >> 4;
    int coL   = nnL * 16 + (laneg & 15);
    bf16x8 pk;
#pragma unroll
    for (int j = 0; j < 8; ++j) pk[j] = f2bf(tile[coL][(hi * 8 + j) * 9 + t]);
    *(bf16x8*)&wtf[(((size_t)t * 16 + kkb) * 32 + nnG0 + nnL) * 512 + laneg * 8] = pk;
  }
}

// ---- x NCHW f32 -> xh chunked-padded bf16 ---------------------------------
__global__ __launch_bounds__(256) void x2xh_kernel(
    const float* __restrict__ x, short* __restrict__ xh) {
  __shared__ float tile[32][33];  // [w][ci]
  const int ch = blockIdx.x;   // 0..15
  const int h  = blockIdx.y;   // 0..31
  const int n  = blockIdx.z;   // 0..31
  const int w0 = threadIdx.x & 31;
  const int c0 = threadIdx.x >> 5;
#pragma unroll
  for (int pass = 0; pass < 4; ++pass) {
    int cir = pass * 8 + c0;
    tile[w0][cir] = x[(((size_t)n * kC + ch * 32 + cir) * kH + h) * kW + w0];
  }
  __syncthreads();
  const int wv = threadIdx.x >> 3;
  const int g4 = (threadIdx.x & 7) * 4;
  bf16x4 pk;
#pragma unroll
  for (int j = 0; j < 4; ++j) pk[j] = f2bf(tile[wv][g4 + j]);
  *(bf16x4*)&xh[(((size_t)n * 16 + ch) * 1156 + (size_t)(h + 1) * 34 + (wv + 1)) * 32 + g4] = pk;
}

// ---- halo zeroing for xh and vh (rows 0/33, cols 0/33 of each plane) ------
__global__ __launch_bounds__(256) void halo_zero_kernel(
    short* __restrict__ xh, short* __restrict__ vh) {
  short* base = (blockIdx.x & 1) ? vh : xh;
  const int plane = blockIdx.x >> 1;  // 0..511 = n*16+ch
  short* dst = base + (size_t)plane * PCH;
  const int t = threadIdx.x;
  if (t < 132) {
    int row, col;
    if (t < 34)       { row = 0;          col = t; }
    else if (t < 68)  { row = 33;         col = t - 34; }
    else if (t < 100) { row = t - 68 + 1; col = 0; }
    else              { row = t - 100 + 1; col = 33; }
    const bf16x8 z = {0, 0, 0, 0, 0, 0, 0, 0};
    short* q = dst + (size_t)(row * 34 + col) * 32;
#pragma unroll
    for (int j = 0; j < 4; ++j) *(bf16x8*)&q[j * 8] = z;
  }
}

// ---- FUSED q/k/v conv3x3 via MFMA implicit shift-GEMM ---------------------
// R12 tile geometry (128sp x 64co, wave = 16co x 128sp, zero B duplication).
// NEW: in-place B rotation (no nxt shadow, -12 arch regs) + (256,3) ->
// 3 waves/SIMD (was 2 at 88+96=184 regs).
__global__ __launch_bounds__(256, 3) void conv_qkv_kernel(
    const short* __restrict__ xin,
    const short* __restrict__ wtq, const short* __restrict__ wtk,
    const short* __restrict__ wtv,
    short* __restrict__ outq, short* __restrict__ outk,
    short* __restrict__ outv) {
  __shared__ __align__(16) short As[3][8192];  // [pos 256][ci 32] bf16, x3
  const int tid  = threadIdx.x;
  const int lane = tid & 63;
  const int l15  = lane & 15, lhi = lane >> 4;
  const int w    = tid >> 6;       // wave 0..3 = co quarter
  const int wbase = tid & 192;

  // 2048 blocks. xcd = bid&7; m = bid>>3 in 0..255:
  //   spt = m&7 (fastest), n = xcd*4 + ((m>>3)&3), co-tile = m>>5 (slowest).
  const int xcd = blockIdx.x & 7;
  const int m   = blockIdx.x >> 3;
  const int co0 = (m >> 5) * 64;
  const int spt = m & 7;
  const int n   = xcd * 4 + ((m >> 3) & 3);
  const int h0  = spt * 4;
  const int sp0 = spt * 128;

  const short* srcA = xin + (size_t)n * (16 * PCH) + (size_t)h0 * (34 * 32);
  const size_t boff = ((size_t)(co0 >> 4) + w) * 512 + lane * 8;
  const short* bp[3] = {wtq + boff, wtk + boff, wtv + boff};

  f32x4 acc[3][8];
#pragma unroll
  for (int c = 0; c < 3; ++c)
#pragma unroll
    for (int mf = 0; mf < 8; ++mf)
#pragma unroll
      for (int r = 0; r < 4; ++r) acc[c][mf][r] = 0.f;

#define STAGE_A(kk, buf)                                                      \
  {                                                                           \
    const short* gA = srcA + (size_t)(kk) * PCH;                              \
    _Pragma("unroll") for (int pass = 0; pass < 4; ++pass)                    \
        gload_lds16(gA + (size_t)(pass * 256 + tid) * 8,                      \
                    &As[buf][(pass * 256 + wbase) * 8]);                      \
  }

  STAGE_A(0, 0);
  STAGE_A(1, 1);
  bf16x8 cur[3];
#pragma unroll
  for (int j = 0; j < 3; ++j)  // b(kk=0, t=0): issued AFTER the two stages
    cur[j] = *(const bf16x8*)&bp[j][0];

  int ab = 0;   // buffer holding stage kk
  int sb = 2;   // buffer to stage kk+2 into
  for (int kk = 0; kk < 16; ++kk) {
    // FIFO oldest-first: newest 7 VM ops = last tap's 3 B reloads +
    // stage(kk+2)'s 4 (issued t==1 of THIS-1 iter). stage(kk) is ancient.
    asm volatile("s_waitcnt vmcnt(7)" ::: "memory");
    __builtin_amdgcn_s_barrier();
#pragma unroll
    for (int t = 0; t < 9; ++t) {
      if (t == 1 && kk < 14) STAGE_A(kk + 2, sb);
      const int dy = t / 3, dx = t % 3;
      bf16x8 a[8];
#pragma unroll
      for (int mf = 0; mf < 8; ++mf) {
        const int pb = ((mf >> 1) + dy) * 34 + (mf & 1) * 16 + l15 + dx;
        a[mf] = *(const bf16x8*)&As[ab][pb * 32 + lhi * 8];
      }
      // next tap's B offset (t==8: next kk's tap 0; kk==15 tail reads
      // in-bounds garbage at wtf[16*16384..], never consumed)
      const int nt  = (t < 8) ? (t + 1) : 0;
      const int nkk = (t < 8) ? kk : kk + 1;
      const size_t bo = (size_t)(nt * 16 + nkk) * 16384;
#pragma unroll
      for (int c = 0; c < 3; ++c) {
        __builtin_amdgcn_s_setprio(1);
#pragma unroll
        for (int mf = 0; mf < 8; ++mf)
          acc[c][mf] = __builtin_amdgcn_mfma_f32_16x16x32_bf16(
              a[mf], cur[c], acc[c][mf], 0, 0, 0);
        __builtin_amdgcn_s_setprio(0);
        // in-place rotate: reload the frag just consumed with tap nt
        cur[c] = *(const bf16x8*)&bp[c][bo];
      }
    }
    ab = (ab == 2) ? 0 : ab + 1;
    sb = (sb == 2) ? 0 : sb + 1;
  }
#undef STAGE_A

  short* outs[3] = {outq, outk, outv};
#pragma unroll
  for (int c = 0; c < 3; ++c) {
    short* out = outs[c];
#pragma unroll
    for (int mf = 0; mf < 8; ++mf)
#pragma unroll
      for (int r = 0; r < 4; ++r) {
        size_t off = ((size_t)n * kHW + sp0 + mf * 16 + lhi * 4 + r) * kC
                     + co0 + w * 16 + l15;
        out[off] = f2bf(acc[c][mf][r]);
      }
  }
}

// ---- conv_o (128co x 128sp), wave = 32co x 128sp (B dedup, R12 pattern) ---
// acc[2][8] = 64 AGPR + ~70 arch -> 3 waves/SIMD at (256,3).
__global__ __launch_bounds__(256, 3) void conv_o_kernel(
    const short* __restrict__ xin, const short* __restrict__ wtf,
    const float* __restrict__ xres, float* __restrict__ out) {
  __shared__ __align__(16) short As[3][8192];
  const int tid  = threadIdx.x;
  const int lane = tid & 63;
  const int l15  = lane & 15, lhi = lane >> 4;
  const int w    = tid >> 6;       // wave 0..3 = co quarter (32 co each)
  const int wbase = tid & 192;

  const int xcd = blockIdx.x & 7;
  const int m   = blockIdx.x >> 3;
  const int co0 = (m >> 5) * 128;
  const int spt = m & 7;
  const int n   = xcd * 4 + ((m >> 3) & 3);
  const int h0  = spt * 4;
  const int sp0 = spt * 128;

  const short* srcA = xin + (size_t)n * (16 * PCH) + (size_t)h0 * (34 * 32);
  const short* bptr = wtf + ((size_t)(co0 >> 4) + w * 2) * 512 + lane * 8;

  f32x4 acc[2][8];
#pragma unroll
  for (int nf = 0; nf < 2; ++nf)
#pragma unroll
    for (int mf = 0; mf < 8; ++mf)
#pragma unroll
      for (int r = 0; r < 4; ++r) acc[nf][mf][r] = 0.f;

#define STAGE_A(kk, buf)                                                      \
  {                                                                           \
    const short* gA = srcA + (size_t)(kk) * PCH;                              \
    _Pragma("unroll") for (int pass = 0; pass < 4; ++pass)                    \
        gload_lds16(gA + (size_t)(pass * 256 + tid) * 8,                      \
                    &As[buf][(pass * 256 + wbase) * 8]);                      \
  }

  STAGE_A(0, 0);
  STAGE_A(1, 1);
  bf16x8 cur[2], nxt[2];
#pragma unroll
  for (int j = 0; j < 2; ++j)
    cur[j] = *(const bf16x8*)&bptr[(size_t)j * 512];

  int ab = 0, sb = 2;
  for (int kk = 0; kk < 16; ++kk) {
    asm volatile("s_waitcnt vmcnt(6)" ::: "memory");
    __builtin_amdgcn_s_barrier();
#pragma unroll
    for (int t = 0; t < 9; ++t) {
      {
        const int nt  = (t < 8) ? (t + 1) : 0;
        const int nkk = (t < 8) ? kk : kk + 1;
        const size_t bo = (size_t)(nt * 16 + nkk) * 16384;
#pragma unroll
        for (int j = 0; j < 2; ++j)
          nxt[j] = *(const bf16x8*)&bptr[bo + (size_t)j * 512];
      }
      if (t == 1 && kk < 14) STAGE_A(kk + 2, sb);
      const int dy = t / 3, dx = t % 3;
      bf16x8 a[8];
#pragma unroll
      for (int mf = 0; mf < 8; ++mf) {
        const int pb = ((mf >> 1) + dy) * 34 + (mf & 1) * 16 + l15 + dx;
        a[mf] = *(const bf16x8*)&As[ab][pb * 32 + lhi * 8];
      }
      __builtin_amdgcn_s_setprio(1);
#pragma unroll
      for (int nf = 0; nf < 2; ++nf)
#pragma unroll
        for (int mf = 0; mf < 8; ++mf)
          acc[nf][mf] = __builtin_amdgcn_mfma_f32_16x16x32_bf16(
              a[mf], cur[nf], acc[nf][mf], 0, 0, 0);
      __builtin_amdgcn_s_setprio(0);
#pragma unroll
      for (int j = 0; j < 2; ++j) cur[j] = nxt[j];
    }
    ab = (ab == 2) ? 0 : ab + 1;
    sb = (sb == 2) ? 0 : sb + 1;
  }
#undef STAGE_A

  // Epilogue: T[64 rows][129] f32 (33 KB in dead As). Row tr = w*16+l15
  // holds co = co0 + (tr>>4)*32 + nf*16 + (tr&15). All acc indices static.
  float* T = (float*)&As[0][0];
#pragma unroll
  for (int nf = 0; nf < 2; ++nf) {
    __syncthreads();
    const int tr = w * 16 + l15;
#pragma unroll
    for (int mf = 0; mf < 8; ++mf)
#pragma unroll
      for (int r = 0; r < 4; ++r)
        T[tr * 129 + mf * 16 + lhi * 4 + r] = acc[nf][mf][r];
    __syncthreads();
#pragma unroll
    for (int it = 0; it < 32; ++it) {
      int idx = it * 256 + tid;
      int trr = idx >> 7, sp = idx & 127;
      int co = co0 + (trr >> 4) * 32 + nf * 16 + (trr & 15);
      size_t off = ((size_t)n * kC + co) * kHW + sp0 + sp;
      out[off] = T[trr * 129 + sp] + xres[off];
    }
  }
}

// ---- MFMA per-pixel attention + fused GN partial sums (R14-verified) ------
__global__ __launch_bounds__(256) void attn_mfma_kernel(
    const short* q, const short* __restrict__ k,
    const short* __restrict__ v, short* virt, float* __restrict__ gsum) {
  __shared__ __align__(16) short Qs[32 * 72];  // [i][c 64 + pad 8]
  __shared__ __align__(16) short Ks[32 * 72];  // [j][c 64 + pad 8]
  __shared__ __align__(16) float Ps[32 * 36];  // [i][j 32 + pad 4]
  __shared__ __align__(16) short Vt[64 * 40];  // [cL][j 32 + pad 8], swizzled
  const int p    = blockIdx.x;
  const int tid  = threadIdx.x;
  const int lane = tid & 63;
  const int l15  = lane & 15, lhi = lane >> 4;
  const int w    = tid >> 6;       // wave 0..3
  const int iq   = w >> 1, jq = w & 1;  // S quadrant

  f32x4 accS = {0.f, 0.f, 0.f, 0.f};
  const int si = tid >> 3;
  const int sc = (tid & 7) * 8;
  for (int c0 = 0; c0 < kC; c0 += 64) {
    __syncthreads();
    {
      size_t g = ((size_t)si * kHW + p) * kC + c0 + sc;
      *(bf16x8*)&Qs[si * 72 + sc] = *(const bf16x8*)&q[g];
      *(bf16x8*)&Ks[si * 72 + sc] = *(const bf16x8*)&k[g];
    }
    __syncthreads();
#pragma unroll
    for (int cs = 0; cs < 2; ++cs) {
      bf16x8 aq = *(const bf16x8*)&Qs[(iq * 16 + l15) * 72 + cs * 32 + lhi * 8];
      bf16x8 bk = *(const bf16x8*)&Ks[(jq * 16 + l15) * 72 + cs * 32 + lhi * 8];
      accS = __builtin_amdgcn_mfma_f32_16x16x32_bf16(aq, bk, accS, 0, 0, 0);
    }
  }
  __syncthreads();
  constexpr float scale = 0.044194173824159216f;  // 1/sqrt(512)
#pragma unroll
  for (int r = 0; r < 4; ++r)
    Ps[(iq * 16 + lhi * 4 + r) * 36 + jq * 16 + l15] = accS[r] * scale;
  __syncthreads();

  {
    const int i  = tid >> 3;
    const int j0 = (tid & 7) * 4;
    float a0 = Ps[i * 36 + j0], a1 = Ps[i * 36 + j0 + 1];
    float a2 = Ps[i * 36 + j0 + 2], a3 = Ps[i * 36 + j0 + 3];
    float mx = fmaxf(fmaxf(a0, a1), fmaxf(a2, a3));
    for (int off = 1; off < 8; off <<= 1) mx = fmaxf(mx, __shfl_xor(mx, off));
    float e0 = __expf(a0 - mx), e1 = __expf(a1 - mx);
    float e2 = __expf(a2 - mx), e3 = __expf(a3 - mx);
    float s = e0 + e1 + e2 + e3;
    for (int off = 1; off < 8; off <<= 1) s += __shfl_xor(s, off);
    const float inv = 1.f / s;
    Ps[i * 36 + j0]     = e0 * inv;
    Ps[i * 36 + j0 + 1] = e1 * inv;
    Ps[i * 36 + j0 + 2] = e2 * inv;
    Ps[i * 36 + j0 + 3] = e3 * inv;
  }
  __syncthreads();

  bf16x8 ap[2];
#pragma unroll
  for (int it = 0; it < 2; ++it) {
    const float* pr = &Ps[(it * 16 + l15) * 36 + lhi * 8];
    float4 lo = *(const float4*)pr;
    float4 hi4 = *(const float4*)(pr + 4);
    ap[it][0] = f2bf(lo.x);  ap[it][1] = f2bf(lo.y);
    ap[it][2] = f2bf(lo.z);  ap[it][3] = f2bf(lo.w);
    ap[it][4] = f2bf(hi4.x); ap[it][5] = f2bf(hi4.y);
    ap[it][6] = f2bf(hi4.z); ap[it][7] = f2bf(hi4.w);
  }
  __syncthreads();  // all reads of Ps done before epilogue reuses it

  float gs[8], gq2[8];
#pragma unroll
  for (int idx = 0; idx < 8; ++idx) { gs[idx] = 0.f; gq2[idx] = 0.f; }

  const f32x4 zacc = {0.f, 0.f, 0.f, 0.f};
  for (int c0 = 0; c0 < kC; c0 += 64) {
    __syncthreads();
    {
      const int j = tid >> 3, c8g = tid & 7;
      bf16x8 vvv = *(const bf16x8*)&v[((size_t)j * kHW + p) * kC + c0 + c8g * 8];
#pragma unroll
      for (int jj = 0; jj < 8; ++jj) {
        int c = c8g * 8 + jj;
        int byte = (c * 80 + j * 2) ^ (((c >> 3) & 7) << 4);
        *(short*)((char*)Vt + byte) = vvv[jj];
      }
    }
    __syncthreads();
    {
      const int c = w * 16 + l15;
      const int byte = (c * 80 + lhi * 16) ^ (((c >> 3) & 7) << 4);
      bf16x8 bv = *(const bf16x8*)((const char*)Vt + byte);
#pragma unroll
      for (int it = 0; it < 2; ++it) {
        f32x4 o = __builtin_amdgcn_mfma_f32_16x16x32_bf16(ap[it], bv, zacc, 0, 0, 0);
#pragma unroll
        for (int r = 0; r < 4; ++r) {
          short ob = f2bf(o[r]);
          virt[((size_t)(it * 16 + lhi * 4 + r) * kHW + p) * kC + c0 + w * 16 + l15] = ob;
          float fv = bf2f(ob);
          gs[it * 4 + r] += fv;
          gq2[it * 4 + r] = fmaf(fv, fv, gq2[it * 4 + r]);
        }
      }
    }
  }

  // GN partial sums: reduce over the 16 l15-lanes sharing (it,lhi,r)
#pragma unroll
  for (int idx = 0; idx < 8; ++idx)
    for (int off = 1; off < 16; off <<= 1) {
      gs[idx]  += __shfl_xor(gs[idx], off);
      gq2[idx] += __shfl_xor(gq2[idx], off);
    }
  __syncthreads();  // Vt reads done; Ps reuse below
  float* SS = Ps;   // [w][32 inst][2] = 256 floats
  if (l15 == 0) {
#pragma unroll
    for (int idx = 0; idx < 8; ++idx) {
      int it = idx >> 2, r = idx & 3;
      int i = it * 16 + lhi * 4 + r;
      SS[(w * 32 + i) * 2]     = gs[idx];
      SS[(w * 32 + i) * 2 + 1] = gq2[idx];
    }
  }
  __syncthreads();
  if (tid < 32) {
    float s = 0.f, q2 = 0.f;
#pragma unroll
    for (int ww = 0; ww < 4; ++ww) {
      s  += SS[(ww * 32 + tid) * 2];
      q2 += SS[(ww * 32 + tid) * 2 + 1];
    }
    atomicAdd(&gsum[tid], s);
    atomicAdd(&gsum[32 + tid], q2);
  }
}

// ---- GN finalize from fused sums ------------------------------------------
__global__ __launch_bounds__(64) void gn_final_kernel(
    const float* __restrict__ gsum, float* __restrict__ stats) {
  if (threadIdx.x < 32) {
    constexpr float invn = 1.f / ((float)kHW * kC);
    float mean = gsum[threadIdx.x] * invn;
    float var = gsum[32 + threadIdx.x] * invn - mean * mean;
    stats[threadIdx.x] = mean;
    stats[32 + threadIdx.x] = rsqrtf(var + 1e-5f);
  }
}

// ---- GN apply + affine + ReLU -> chunked-padded bf16 ----------------------
__global__ __launch_bounds__(256) void gn_apply_kernel(
    const short* __restrict__ virt, const float* __restrict__ stats,
    const float* __restrict__ gamma, const float* __restrict__ beta,
    short* __restrict__ vh) {
  const size_t g = (size_t)blockIdx.x * 256 + threadIdx.x;
  const int i    = (int)(g >> 16);
  const int rest = (int)(g & 65535);
  const int p    = rest >> 6;
  const int c8g  = rest & 63;
  const int ci   = c8g * 8;
  const float mean = stats[i];
  const float rstd = stats[32 + i];
  bf16x8 vv = *(const bf16x8*)&virt[((size_t)i * kHW + p) * kC + ci];
  const float4 ga = ((const float4*)gamma)[c8g * 2];
  const float4 gb = ((const float4*)gamma)[c8g * 2 + 1];
  const float4 ba = ((const float4*)beta)[c8g * 2];
  const float4 bb = ((const float4*)beta)[c8g * 2 + 1];
  const float gv[8] = {ga.x, ga.y, ga.z, ga.w, gb.x, gb.y, gb.z, gb.w};
  const float bv[8] = {ba.x, ba.y, ba.z, ba.w, bb.x, bb.y, bb.z, bb.w};
  bf16x8 o;
#pragma unroll
  for (int jj = 0; jj < 8; ++jj) {
    float f = (bf2f(vv[jj]) - mean) * rstd;
    f = fmaxf(fmaf(f, gv[jj], bv[jj]), 0.f);
    o[jj] = f2bf(f);
  }
  const size_t dst =
      (((size_t)i * 16 + (ci >> 5)) * 1156 + (size_t)((p >> 5) + 1) * 34 + (p & 31) + 1) * 32
      + (ci & 31);
  *(bf16x8*)&vh[dst] = o;
}

}  // namespace

extern "C" void kernel_launch(void* const* d_in, const int* in_sizes, int n_in,
                              void* d_out, int out_size, void* d_ws,
                              size_t ws_size, hipStream_t stream) {
  const float* x     = (const float*)d_in[0];
  const float* w_q   = (const float*)d_in[1];
  const float* w_k   = (const float*)d_in[2];
  const float* w_v   = (const float*)d_in[3];
  const float* w_o   = (const float*)d_in[4];
  const float* gamma = (const float*)d_in[5];
  const float* beta  = (const float*)d_in[6];

  short* ws    = (short*)d_ws;
  short* wtf_q = ws;
  short* wtf_k = wtf_q + WTF_ELEMS;
  short* wtf_v = wtf_k + WTF_ELEMS;
  short* wtf_o = wtf_v + WTF_ELEMS;
  short* xh    = wtf_o + WTF_ELEMS;
  short* vh    = xh + XH_ELEMS;
  short* qb    = vh + XH_ELEMS;
  short* kb    = qb + QKV_ELEMS;
  short* vb    = kb + QKV_ELEMS;
  float* stats = (float*)(vb + QKV_ELEMS);  // 64 floats
  float* gsum  = stats + 64;                // 64 floats (sum, sumsq)
  short* virt  = qb;  // attn writes per-position after reading q
  // zero halos (rows/cols 0 & 33 of each padded plane) + fused-GN accumulators
  halo_zero_kernel<<<1024, 256, 0, stream>>>(xh, vh);
  hipMemsetAsync(gsum, 0, 64 * sizeof(float), stream);

  wtf_pack_kernel<<<dim3(16, 16, 4), 256, 0, stream>>>(
      w_q, w_k, w_v, w_o, wtf_q, wtf_k, wtf_v, wtf_o);

  x2xh_kernel<<<dim3(16, 32, 32), 256, 0, stream>>>(x, xh);

  conv_qkv_kernel<<<2048, 256, 0, stream>>>(xh, wtf_q, wtf_k, wtf_v,
                                            qb, kb, vb);

  attn_mfma_kernel<<<kHW, 256, 0, stream>>>(qb, kb, vb, virt, gsum);

  gn_final_kernel<<<1, 64, 0, stream>>>(gsum, stats);
  gn_apply_kernel<<<(int)(QKV_ELEMS / 8 / 256), 256, 0, stream>>>(
      virt, stats, gamma, beta, vh);

  conv_o_kernel<<<1024, 256, 0, stream>>>(vh, wtf_o, x, (float*)d_out);
}

// Round 17
// 543.994 us; speedup vs baseline: 1.1085x; 1.0171x over previous
//
#include <hip/hip_runtime.h>

namespace {

constexpr int kN  = 32;
constexpr int kC  = 512;
constexpr int kH  = 32;
constexpr int kW  = 32;
constexpr int kHW = kH * kW;

// bf16 chunked-padded activation layout: [n][chunk=ci/32][34 rows][34 cols][32 ci]
constexpr int PCH   = 36992;                 // 34*34*32 elems per (n,chunk) plane
constexpr size_t WTF_ELEMS = (size_t)9 * kC * kC;          // 2,359,296 bf16
constexpr size_t XH_ELEMS  = (size_t)kN * 16 * PCH;        // 18,939,904 bf16
constexpr size_t QKV_ELEMS = (size_t)kN * kHW * kC;        // 16,777,216 bf16

using bf16x8 = __attribute__((ext_vector_type(8))) short;
using bf16x4 = __attribute__((ext_vector_type(4))) short;
using f32x4  = __attribute__((ext_vector_type(4))) float;

__device__ __forceinline__ float bf2f(short s) {
  unsigned u = ((unsigned)(unsigned short)s) << 16;
  return __builtin_bit_cast(float, u);
}
__device__ __forceinline__ short f2bf(float f) {
  unsigned u = __builtin_bit_cast(unsigned, f);
  u += 0x7FFFu + ((u >> 16) & 1u);
  return (short)(u >> 16);
}
__device__ __forceinline__ void gload_lds16(const void* g, void* l) {
  __builtin_amdgcn_global_load_lds(
      (const __attribute__((address_space(1))) void*)g,
      (__attribute__((address_space(3))) void*)l, 16, 0, 0);
}

// ---- weight pack: q/k/v -> MERGED [t][kk][nnG][c3][512]; o -> own buffer --
__global__ __launch_bounds__(256) void wtf_pack_kernel(
    const float* __restrict__ wq, const float* __restrict__ wk,
    const float* __restrict__ wv, const float* __restrict__ wo,
    short* __restrict__ wqkv, short* __restrict__ wo_out) {
  const float* wsrc[4] = {wq, wk, wv, wo};
  const int z = blockIdx.z;
  const float* w = wsrc[z];
  __shared__ float tile[32][289];  // [co][ci*9+t]
  const int co0 = blockIdx.x * 32;
  const int ci0 = blockIdx.y * 32;
  for (int idx = threadIdx.x; idx < 32 * 288; idx += 256) {
    int c = idx % 288, r = idx / 288;
    tile[r][c] = w[(size_t)(co0 + r) * (kC * 9) + (size_t)ci0 * 9 + c];
  }
  __syncthreads();
  const int kkb  = ci0 >> 5;
  const int nnG0 = co0 >> 4;
  for (int g = threadIdx.x; g < 9 * 2 * 64; g += 256) {
    int laneg = g & 63;
    int nnL   = (g >> 6) & 1;
    int t     = g >> 7;  // 0..8
    int hi    = laneg >> 4;
    int coL   = nnL * 16 + (laneg & 15);
    bf16x8 pk;
#pragma unroll
    for (int j = 0; j < 8; ++j) pk[j] = f2bf(tile[coL][(hi * 8 + j) * 9 + t]);
    if (z < 3) {
      *(bf16x8*)&wqkv[((((size_t)t * 16 + kkb) * 32 + nnG0 + nnL) * 3 + z) * 512
                      + laneg * 8] = pk;
    } else {
      *(bf16x8*)&wo_out[(((size_t)t * 16 + kkb) * 32 + nnG0 + nnL) * 512
                        + laneg * 8] = pk;
    }
  }
}

// ---- x NCHW f32 -> xh chunked-padded bf16 ---------------------------------
__global__ __launch_bounds__(256) void x2xh_kernel(
    const float* __restrict__ x, short* __restrict__ xh) {
  __shared__ float tile[32][33];  // [w][ci]
  const int ch = blockIdx.x;   // 0..15
  const int h  = blockIdx.y;   // 0..31
  const int n  = blockIdx.z;   // 0..31
  const int w0 = threadIdx.x & 31;
  const int c0 = threadIdx.x >> 5;
#pragma unroll
  for (int pass = 0; pass < 4; ++pass) {
    int cir = pass * 8 + c0;
    tile[w0][cir] = x[(((size_t)n * kC + ch * 32 + cir) * kH + h) * kW + w0];
  }
  __syncthreads();
  const int wv = threadIdx.x >> 3;
  const int g4 = (threadIdx.x & 7) * 4;
  bf16x4 pk;
#pragma unroll
  for (int j = 0; j < 4; ++j) pk[j] = f2bf(tile[wv][g4 + j]);
  *(bf16x4*)&xh[(((size_t)n * 16 + ch) * 1156 + (size_t)(h + 1) * 34 + (wv + 1)) * 32 + g4] = pk;
}

// ---- halo zeroing for xh and vh (rows 0/33, cols 0/33 of each plane) ------
__global__ __launch_bounds__(256) void halo_zero_kernel(
    short* __restrict__ xh, short* __restrict__ vh) {
  short* base = (blockIdx.x & 1) ? vh : xh;
  const int plane = blockIdx.x >> 1;  // 0..511 = n*16+ch
  short* dst = base + (size_t)plane * PCH;
  const int t = threadIdx.x;
  if (t < 132) {
    int row, col;
    if (t < 34)       { row = 0;          col = t; }
    else if (t < 68)  { row = 33;         col = t - 34; }
    else if (t < 100) { row = t - 68 + 1; col = 0; }
    else              { row = t - 100 + 1; col = 33; }
    const bf16x8 z = {0, 0, 0, 0, 0, 0, 0, 0};
    short* q = dst + (size_t)(row * 34 + col) * 32;
#pragma unroll
    for (int j = 0; j < 4; ++j) *(bf16x8*)&q[j * 8] = z;
  }
}

// ---- FUSED q/k/v conv3x3 via MFMA implicit shift-GEMM (R16 + merged B) ----
__global__ __launch_bounds__(256, 3) void conv_qkv_kernel(
    const short* __restrict__ xin, const short* __restrict__ wqkv,
    short* __restrict__ outq, short* __restrict__ outk,
    short* __restrict__ outv) {
  __shared__ __align__(16) short As[3][8192];  // [pos 256][ci 32] bf16, x3
  const int tid  = threadIdx.x;
  const int lane = tid & 63;
  const int l15  = lane & 15, lhi = lane >> 4;
  const int w    = tid >> 6;       // wave 0..3 = co quarter
  const int wbase = tid & 192;

  // 2048 blocks. xcd = bid&7; m = bid>>3 in 0..255:
  //   spt = m&7 (fastest), n = xcd*4 + ((m>>3)&3), co-tile = m>>5 (slowest).
  const int xcd = blockIdx.x & 7;
  const int m   = blockIdx.x >> 3;
  const int co0 = (m >> 5) * 64;
  const int spt = m & 7;
  const int n   = xcd * 4 + ((m >> 3) & 3);
  const int h0  = spt * 4;
  const int sp0 = spt * 128;

  const short* srcA = xin + (size_t)n * (16 * PCH) + (size_t)h0 * (34 * 32);
  // merged B: [t*16+kk][nnG][c3][512]; per-wave base at its nnG quarter
  const short* bbase = wqkv + ((size_t)(co0 >> 4) + w) * 1536 + lane * 8;

  f32x4 acc[3][8];
#pragma unroll
  for (int c = 0; c < 3; ++c)
#pragma unroll
    for (int mf = 0; mf < 8; ++mf)
#pragma unroll
      for (int r = 0; r < 4; ++r) acc[c][mf][r] = 0.f;

#define STAGE_A(kk, buf)                                                      \
  {                                                                           \
    const short* gA = srcA + (size_t)(kk) * PCH;                              \
    _Pragma("unroll") for (int pass = 0; pass < 4; ++pass)                    \
        gload_lds16(gA + (size_t)(pass * 256 + tid) * 8,                      \
                    &As[buf][(pass * 256 + wbase) * 8]);                      \
  }

  STAGE_A(0, 0);
  STAGE_A(1, 1);
  bf16x8 cur[3];
#pragma unroll
  for (int j = 0; j < 3; ++j)  // b(kk=0, t=0): issued AFTER the two stages
    cur[j] = *(const bf16x8*)&bbase[(size_t)j * 512];

  int ab = 0;   // buffer holding stage kk
  int sb = 2;   // buffer to stage kk+2 into
  for (int kk = 0; kk < 16; ++kk) {
    // FIFO oldest-first: newest 7 VM ops = last tap's 3 B reloads +
    // stage(kk+1)'s 4. stage(kk) is ancient -> retired.
    asm volatile("s_waitcnt vmcnt(7)" ::: "memory");
    __builtin_amdgcn_s_barrier();
#pragma unroll
    for (int t = 0; t < 9; ++t) {
      if (t == 1 && kk < 14) STAGE_A(kk + 2, sb);
      const int dy = t / 3, dx = t % 3;
      bf16x8 a[8];
#pragma unroll
      for (int mf = 0; mf < 8; ++mf) {
        const int pb = ((mf >> 1) + dy) * 34 + (mf & 1) * 16 + l15 + dx;
        a[mf] = *(const bf16x8*)&As[ab][pb * 32 + lhi * 8];
      }
      // next tap's B offset (t==8: next kk's tap 0; kk==15 tail reads
      // in-bounds garbage at wqkv[16*49152..], never consumed)
      const int nt  = (t < 8) ? (t + 1) : 0;
      const int nkk = (t < 8) ? kk : kk + 1;
      const size_t bo = (size_t)(nt * 16 + nkk) * 49152;
      const short* brel = &bbase[bo];
#pragma unroll
      for (int c = 0; c < 3; ++c) {
        __builtin_amdgcn_s_setprio(1);
#pragma unroll
        for (int mf = 0; mf < 8; ++mf)
          acc[c][mf] = __builtin_amdgcn_mfma_f32_16x16x32_bf16(
              a[mf], cur[c], acc[c][mf], 0, 0, 0);
        __builtin_amdgcn_s_setprio(0);
        // in-place rotate: one base, imm offsets 0/1024/2048 B
        cur[c] = *(const bf16x8*)&brel[(size_t)c * 512];
      }
    }
    ab = (ab == 2) ? 0 : ab + 1;
    sb = (sb == 2) ? 0 : sb + 1;
  }
#undef STAGE_A

  short* outs[3] = {outq, outk, outv};
#pragma unroll
  for (int c = 0; c < 3; ++c) {
    short* out = outs[c];
#pragma unroll
    for (int mf = 0; mf < 8; ++mf)
#pragma unroll
      for (int r = 0; r < 4; ++r) {
        size_t off = ((size_t)n * kHW + sp0 + mf * 16 + lhi * 4 + r) * kC
                     + co0 + w * 16 + l15;
        out[off] = f2bf(acc[c][mf][r]);
      }
  }
}

// ---- conv_o (128co x 128sp), wave = 32co x 128sp (R16-verified, frozen) ---
__global__ __launch_bounds__(256, 3) void conv_o_kernel(
    const short* __restrict__ xin, const short* __restrict__ wtf,
    const float* __restrict__ xres, float* __restrict__ out) {
  __shared__ __align__(16) short As[3][8192];
  const int tid  = threadIdx.x;
  const int lane = tid & 63;
  const int l15  = lane & 15, lhi = lane >> 4;
  const int w    = tid >> 6;       // wave 0..3 = co quarter (32 co each)
  const int wbase = tid & 192;

  const int xcd = blockIdx.x & 7;
  const int m   = blockIdx.x >> 3;
  const int co0 = (m >> 5) * 128;
  const int spt = m & 7;
  const int n   = xcd * 4 + ((m >> 3) & 3);
  const int h0  = spt * 4;
  const int sp0 = spt * 128;

  const short* srcA = xin + (size_t)n * (16 * PCH) + (size_t)h0 * (34 * 32);
  const short* bptr = wtf + ((size_t)(co0 >> 4) + w * 2) * 512 + lane * 8;

  f32x4 acc[2][8];
#pragma unroll
  for (int nf = 0; nf < 2; ++nf)
#pragma unroll
    for (int mf = 0; mf < 8; ++mf)
#pragma unroll
      for (int r = 0; r < 4; ++r) acc[nf][mf][r] = 0.f;

#define STAGE_A(kk, buf)                                                      \
  {                                                                           \
    const short* gA = srcA + (size_t)(kk) * PCH;                              \
    _Pragma("unroll") for (int pass = 0; pass < 4; ++pass)                    \
        gload_lds16(gA + (size_t)(pass * 256 + tid) * 8,                      \
                    &As[buf][(pass * 256 + wbase) * 8]);                      \
  }

  STAGE_A(0, 0);
  STAGE_A(1, 1);
  bf16x8 cur[2], nxt[2];
#pragma unroll
  for (int j = 0; j < 2; ++j)
    cur[j] = *(const bf16x8*)&bptr[(size_t)j * 512];

  int ab = 0, sb = 2;
  for (int kk = 0; kk < 16; ++kk) {
    asm volatile("s_waitcnt vmcnt(6)" ::: "memory");
    __builtin_amdgcn_s_barrier();
#pragma unroll
    for (int t = 0; t < 9; ++t) {
      {
        const int nt  = (t < 8) ? (t + 1) : 0;
        const int nkk = (t < 8) ? kk : kk + 1;
        const size_t bo = (size_t)(nt * 16 + nkk) * 16384;
#pragma unroll
        for (int j = 0; j < 2; ++j)
          nxt[j] = *(const bf16x8*)&bptr[bo + (size_t)j * 512];
      }
      if (t == 1 && kk < 14) STAGE_A(kk + 2, sb);
      const int dy = t / 3, dx = t % 3;
      bf16x8 a[8];
#pragma unroll
      for (int mf = 0; mf < 8; ++mf) {
        const int pb = ((mf >> 1) + dy) * 34 + (mf & 1) * 16 + l15 + dx;
        a[mf] = *(const bf16x8*)&As[ab][pb * 32 + lhi * 8];
      }
      __builtin_amdgcn_s_setprio(1);
#pragma unroll
      for (int nf = 0; nf < 2; ++nf)
#pragma unroll
        for (int mf = 0; mf < 8; ++mf)
          acc[nf][mf] = __builtin_amdgcn_mfma_f32_16x16x32_bf16(
              a[mf], cur[nf], acc[nf][mf], 0, 0, 0);
      __builtin_amdgcn_s_setprio(0);
#pragma unroll
      for (int j = 0; j < 2; ++j) cur[j] = nxt[j];
    }
    ab = (ab == 2) ? 0 : ab + 1;
    sb = (sb == 2) ? 0 : sb + 1;
  }
#undef STAGE_A

  float* T = (float*)&As[0][0];
#pragma unroll
  for (int nf = 0; nf < 2; ++nf) {
    __syncthreads();
    const int tr = w * 16 + l15;
#pragma unroll
    for (int mf = 0; mf < 8; ++mf)
#pragma unroll
      for (int r = 0; r < 4; ++r)
        T[tr * 129 + mf * 16 + lhi * 4 + r] = acc[nf][mf][r];
    __syncthreads();
#pragma unroll
    for (int it = 0; it < 32; ++it) {
      int idx = it * 256 + tid;
      int trr = idx >> 7, sp = idx & 127;
      int co = co0 + (trr >> 4) * 32 + nf * 16 + (trr & 15);
      size_t off = ((size_t)n * kC + co) * kHW + sp0 + sp;
      out[off] = T[trr * 129 + sp] + xres[off];
    }
  }
}

// ---- MFMA per-pixel attention + fused GN sums, T14 double-buffered --------
__global__ __launch_bounds__(256) void attn_mfma_kernel(
    const short* q, const short* __restrict__ k,
    const short* __restrict__ v, short* virt, float* __restrict__ gsum) {
  __shared__ __align__(16) short Qs[2][32 * 72];
  __shared__ __align__(16) short Ks[2][32 * 72];
  __shared__ __align__(16) float Ps[32 * 36];
  __shared__ __align__(16) short Vt[2][64 * 40];
  const int p    = blockIdx.x;
  const int tid  = threadIdx.x;
  const int lane = tid & 63;
  const int l15  = lane & 15, lhi = lane >> 4;
  const int w    = tid >> 6;       // wave 0..3
  const int iq   = w >> 1, jq = w & 1;  // S quadrant

  f32x4 accS = {0.f, 0.f, 0.f, 0.f};
  const int si = tid >> 3;
  const int sc = (tid & 7) * 8;
  const size_t gstep = ((size_t)si * kHW + p) * kC + sc;
  bf16x8 rq = *(const bf16x8*)&q[gstep];
  bf16x8 rk = *(const bf16x8*)&k[gstep];
  for (int i = 0; i < 8; ++i) {
    const int cb = i & 1;
    *(bf16x8*)&Qs[cb][si * 72 + sc] = rq;
    *(bf16x8*)&Ks[cb][si * 72 + sc] = rk;
    if (i < 7) {  // issue next tile's reg loads; land under this tile's MFMA
      rq = *(const bf16x8*)&q[gstep + (i + 1) * 64];
      rk = *(const bf16x8*)&k[gstep + (i + 1) * 64];
    }
    __syncthreads();  // writes to cb visible; prior reads of cb done (i-2's
                      // sync ordered them before i-1's writes to cb^1)
#pragma unroll
    for (int cs = 0; cs < 2; ++cs) {
      bf16x8 aq = *(const bf16x8*)&Qs[cb][(iq * 16 + l15) * 72 + cs * 32 + lhi * 8];
      bf16x8 bk = *(const bf16x8*)&Ks[cb][(jq * 16 + l15) * 72 + cs * 32 + lhi * 8];
      accS = __builtin_amdgcn_mfma_f32_16x16x32_bf16(aq, bk, accS, 0, 0, 0);
    }
  }
  __syncthreads();
  constexpr float scale = 0.044194173824159216f;  // 1/sqrt(512)
#pragma unroll
  for (int r = 0; r < 4; ++r)
    Ps[(iq * 16 + lhi * 4 + r) * 36 + jq * 16 + l15] = accS[r] * scale;
  __syncthreads();

  {
    const int i  = tid >> 3;
    const int j0 = (tid & 7) * 4;
    float a0 = Ps[i * 36 + j0], a1 = Ps[i * 36 + j0 + 1];
    float a2 = Ps[i * 36 + j0 + 2], a3 = Ps[i * 36 + j0 + 3];
    float mx = fmaxf(fmaxf(a0, a1), fmaxf(a2, a3));
    for (int off = 1; off < 8; off <<= 1) mx = fmaxf(mx, __shfl_xor(mx, off));
    float e0 = __expf(a0 - mx), e1 = __expf(a1 - mx);
    float e2 = __expf(a2 - mx), e3 = __expf(a3 - mx);
    float s = e0 + e1 + e2 + e3;
    for (int off = 1; off < 8; off <<= 1) s += __shfl_xor(s, off);
    const float inv = 1.f / s;
    Ps[i * 36 + j0]     = e0 * inv;
    Ps[i * 36 + j0 + 1] = e1 * inv;
    Ps[i * 36 + j0 + 2] = e2 * inv;
    Ps[i * 36 + j0 + 3] = e3 * inv;
  }
  __syncthreads();

  bf16x8 ap[2];
#pragma unroll
  for (int it = 0; it < 2; ++it) {
    const float* pr = &Ps[(it * 16 + l15) * 36 + lhi * 8];
    float4 lo = *(const float4*)pr;
    float4 hi4 = *(const float4*)(pr + 4);
    ap[it][0] = f2bf(lo.x);  ap[it][1] = f2bf(lo.y);
    ap[it][2] = f2bf(lo.z);  ap[it][3] = f2bf(lo.w);
    ap[it][4] = f2bf(hi4.x); ap[it][5] = f2bf(hi4.y);
    ap[it][6] = f2bf(hi4.z); ap[it][7] = f2bf(hi4.w);
  }
  __syncthreads();  // all reads of Ps done before epilogue reuses it

  float gs[8], gq2[8];
#pragma unroll
  for (int idx = 0; idx < 8; ++idx) { gs[idx] = 0.f; gq2[idx] = 0.f; }

  const f32x4 zacc = {0.f, 0.f, 0.f, 0.f};
  const int vj = tid >> 3, vc8 = tid & 7;
  const size_t vstep = ((size_t)vj * kHW + p) * kC + vc8 * 8;
  bf16x8 rv = *(const bf16x8*)&v[vstep];
  for (int i = 0; i < 8; ++i) {
    const int cb = i & 1;
    {
      char* vtb = (char*)&Vt[cb][0];
#pragma unroll
      for (int jj = 0; jj < 8; ++jj) {
        int c = vc8 * 8 + jj;
        int byte = (c * 80 + vj * 2) ^ (((c >> 3) & 7) << 4);
        *(short*)(vtb + byte) = rv[jj];
      }
    }
    if (i < 7) rv = *(const bf16x8*)&v[vstep + (i + 1) * 64];
    __syncthreads();
    {
      const int c0 = i * 64;
      const int c = w * 16 + l15;
      const int byte = (c * 80 + lhi * 16) ^ (((c >> 3) & 7) << 4);
      bf16x8 bv = *(const bf16x8*)((const char*)&Vt[cb][0] + byte);
#pragma unroll
      for (int it = 0; it < 2; ++it) {
        f32x4 o = __builtin_amdgcn_mfma_f32_16x16x32_bf16(ap[it], bv, zacc, 0, 0, 0);
#pragma unroll
        for (int r = 0; r < 4; ++r) {
          short ob = f2bf(o[r]);
          virt[((size_t)(it * 16 + lhi * 4 + r) * kHW + p) * kC + c0 + w * 16 + l15] = ob;
          float fv = bf2f(ob);
          gs[it * 4 + r] += fv;
          gq2[it * 4 + r] = fmaf(fv, fv, gq2[it * 4 + r]);
        }
      }
    }
  }

  // GN partial sums: reduce over the 16 l15-lanes sharing (it,lhi,r)
#pragma unroll
  for (int idx = 0; idx < 8; ++idx)
    for (int off = 1; off < 16; off <<= 1) {
      gs[idx]  += __shfl_xor(gs[idx], off);
      gq2[idx] += __shfl_xor(gq2[idx], off);
    }
  __syncthreads();
  float* SS = Ps;   // [w][32 inst][2] = 256 floats
  if (l15 == 0) {
#pragma unroll
    for (int idx = 0; idx < 8; ++idx) {
      int it = idx >> 2, r = idx & 3;
      int i = it * 16 + lhi * 4 + r;
      SS[(w * 32 + i) * 2]     = gs[idx];
      SS[(w * 32 + i) * 2 + 1] = gq2[idx];
    }
  }
  __syncthreads();
  if (tid < 32) {
    float s = 0.f, q2 = 0.f;
#pragma unroll
    for (int ww = 0; ww < 4; ++ww) {
      s  += SS[(ww * 32 + tid) * 2];
      q2 += SS[(ww * 32 + tid) * 2 + 1];
    }
    atomicAdd(&gsum[tid], s);
    atomicAdd(&gsum[32 + tid], q2);
  }
}

// ---- GN finalize from fused sums ------------------------------------------
__global__ __launch_bounds__(64) void gn_final_kernel(
    const float* __restrict__ gsum, float* __restrict__ stats) {
  if (threadIdx.x < 32) {
    constexpr float invn = 1.f / ((float)kHW * kC);
    float mean = gsum[threadIdx.x] * invn;
    float var = gsum[32 + threadIdx.x] * invn - mean * mean;
    stats[threadIdx.x] = mean;
    stats[32 + threadIdx.x] = rsqrtf(var + 1e-5f);
  }
}

// ---- GN apply + affine + ReLU -> chunked-padded bf16 ----------------------
__global__ __launch_bounds__(256) void gn_apply_kernel(
    const short* __restrict__ virt, const float* __restrict__ stats,
    const float* __restrict__ gamma, const float* __restrict__ beta,
    short* __restrict__ vh) {
  const size_t g = (size_t)blockIdx.x * 256 + threadIdx.x;
  const int i    = (int)(g >> 16);
  const int rest = (int)(g & 65535);
  const int p    = rest >> 6;
  const int c8g  = rest & 63;
  const int ci   = c8g * 8;
  const float mean = stats[i];
  const float rstd = stats[32 + i];
  bf16x8 vv = *(const bf16x8*)&virt[((size_t)i * kHW + p) * kC + ci];
  const float4 ga = ((const float4*)gamma)[c8g * 2];
  const float4 gb = ((const float4*)gamma)[c8g * 2 + 1];
  const float4 ba = ((const float4*)beta)[c8g * 2];
  const float4 bb = ((const float4*)beta)[c8g * 2 + 1];
  const float gv[8] = {ga.x, ga.y, ga.z, ga.w, gb.x, gb.y, gb.z, gb.w};
  const float bv[8] = {ba.x, ba.y, ba.z, ba.w, bb.x, bb.y, bb.z, bb.w};
  bf16x8 o;
#pragma unroll
  for (int jj = 0; jj < 8; ++jj) {
    float f = (bf2f(vv[jj]) - mean) * rstd;
    f = fmaxf(fmaf(f, gv[jj], bv[jj]), 0.f);
    o[jj] = f2bf(f);
  }
  const size_t dst =
      (((size_t)i * 16 + (ci >> 5)) * 1156 + (size_t)((p >> 5) + 1) * 34 + (p & 31) + 1) * 32
      + (ci & 31);
  *(bf16x8*)&vh[dst] = o;
}

}  // namespace

extern "C" void kernel_launch(void* const* d_in, const int* in_sizes, int n_in,
                              void* d_out, int out_size, void* d_ws,
                              size_t ws_size, hipStream_t stream) {
  const float* x     = (const float*)d_in[0];
  const float* w_q   = (const float*)d_in[1];
  const float* w_k   = (const float*)d_in[2];
  const float* w_v   = (const float*)d_in[3];
  const float* w_o   = (const float*)d_in[4];
  const float* gamma = (const float*)d_in[5];
  const float* beta  = (const float*)d_in[6];

  short* ws    = (short*)d_ws;
  short* wqkv  = ws;                       // merged q/k/v weights (3x WTF)
  short* wtf_o = wqkv + 3 * WTF_ELEMS;
  short* xh    = wtf_o + WTF_ELEMS;
  short* vh    = xh + XH_ELEMS;
  short* qb    = vh + XH_ELEMS;
  short* kb    = qb + QKV_ELEMS;
  short* vb    = kb + QKV_ELEMS;
  float* stats = (float*)(vb + QKV_ELEMS);  // 64 floats
  float* gsum  = stats + 64;                // 64 floats (sum, sumsq)
  short* virt  = qb;  // attn writes per-position after reading q
  halo_zero_kernel<<<1024, 256, 0, stream>>>(xh, vh);
  hipMemsetAsync(gsum, 0, 64 * sizeof(float), stream);

  wtf_pack_kernel<<<dim3(16, 16, 4), 256, 0, stream>>>(
      w_q, w_k, w_v, w_o, wqkv, wtf_o);

  x2xh_kernel<<<dim3(16, 32, 32), 256, 0, stream>>>(x, xh);

  conv_qkv_kernel<<<2048, 256, 0, stream>>>(xh, wqkv, qb, kb, vb);

  attn_mfma_kernel<<<kHW, 256, 0, stream>>>(qb, kb, vb, virt, gsum);

  gn_final_kernel<<<1, 64, 0, stream>>>(gsum, stats);
  gn_apply_kernel<<<(int)(QKV_ELEMS / 8 / 256), 256, 0, stream>>>(
      virt, stats, gamma, beta, vh);

  conv_o_kernel<<<1024, 256, 0, stream>>>(vh, wtf_o, x, (float*)d_out);
}

// Round 18
// 535.329 us; speedup vs baseline: 1.1265x; 1.0162x over previous
//
#include <hip/hip_runtime.h>

namespace {

constexpr int kN  = 32;
constexpr int kC  = 512;
constexpr int kH  = 32;
constexpr int kW  = 32;
constexpr int kHW = kH * kW;

// bf16 chunked-padded activation layout: [n][chunk=ci/32][34 rows][34 cols][32 ci]
constexpr int PCH   = 36992;                 // 34*34*32 elems per (n,chunk) plane
constexpr size_t WTF_ELEMS = (size_t)9 * kC * kC;          // 2,359,296 bf16
constexpr size_t XH_ELEMS  = (size_t)kN * 16 * PCH;        // 18,939,904 bf16
constexpr size_t QKV_ELEMS = (size_t)kN * kHW * kC;        // 16,777,216 bf16

using bf16x8 = __attribute__((ext_vector_type(8))) short;
using bf16x4 = __attribute__((ext_vector_type(4))) short;
using f32x4  = __attribute__((ext_vector_type(4))) float;

__device__ __forceinline__ float bf2f(short s) {
  unsigned u = ((unsigned)(unsigned short)s) << 16;
  return __builtin_bit_cast(float, u);
}
__device__ __forceinline__ short f2bf(float f) {
  unsigned u = __builtin_bit_cast(unsigned, f);
  u += 0x7FFFu + ((u >> 16) & 1u);
  return (short)(u >> 16);
}
__device__ __forceinline__ void gload_lds16(const void* g, void* l) {
  __builtin_amdgcn_global_load_lds(
      (const __attribute__((address_space(1))) void*)g,
      (__attribute__((address_space(3))) void*)l, 16, 0, 0);
}

// ---- weight pack: q/k/v -> MERGED [t][kk][nnG][c3][512]; o -> own buffer --
__global__ __launch_bounds__(256) void wtf_pack_kernel(
    const float* __restrict__ wq, const float* __restrict__ wk,
    const float* __restrict__ wv, const float* __restrict__ wo,
    short* __restrict__ wqkv, short* __restrict__ wo_out) {
  const float* wsrc[4] = {wq, wk, wv, wo};
  const int z = blockIdx.z;
  const float* w = wsrc[z];
  __shared__ float tile[32][289];  // [co][ci*9+t]
  const int co0 = blockIdx.x * 32;
  const int ci0 = blockIdx.y * 32;
  for (int idx = threadIdx.x; idx < 32 * 288; idx += 256) {
    int c = idx % 288, r = idx / 288;
    tile[r][c] = w[(size_t)(co0 + r) * (kC * 9) + (size_t)ci0 * 9 + c];
  }
  __syncthreads();
  const int kkb  = ci0 >> 5;
  const int nnG0 = co0 >> 4;
  for (int g = threadIdx.x; g < 9 * 2 * 64; g += 256) {
    int laneg = g & 63;
    int nnL   = (g >> 6) & 1;
    int t     = g >> 7;  // 0..8
    int hi    = laneg >> 4;
    int coL   = nnL * 16 + (laneg & 15);
    bf16x8 pk;
#pragma unroll
    for (int j = 0; j < 8; ++j) pk[j] = f2bf(tile[coL][(hi * 8 + j) * 9 + t]);
    if (z < 3) {
      *(bf16x8*)&wqkv[((((size_t)t * 16 + kkb) * 32 + nnG0 + nnL) * 3 + z) * 512
                      + laneg * 8] = pk;
    } else {
      *(bf16x8*)&wo_out[(((size_t)t * 16 + kkb) * 32 + nnG0 + nnL) * 512
                        + laneg * 8] = pk;
    }
  }
}

// ---- x NCHW f32 -> xh chunked-padded bf16 ---------------------------------
__global__ __launch_bounds__(256) void x2xh_kernel(
    const float* __restrict__ x, short* __restrict__ xh) {
  __shared__ float tile[32][33];  // [w][ci]
  const int ch = blockIdx.x;   // 0..15
  const int h  = blockIdx.y;   // 0..31
  const int n  = blockIdx.z;   // 0..31
  const int w0 = threadIdx.x & 31;
  const int c0 = threadIdx.x >> 5;
#pragma unroll
  for (int pass = 0; pass < 4; ++pass) {
    int cir = pass * 8 + c0;
    tile[w0][cir] = x[(((size_t)n * kC + ch * 32 + cir) * kH + h) * kW + w0];
  }
  __syncthreads();
  const int wv = threadIdx.x >> 3;
  const int g4 = (threadIdx.x & 7) * 4;
  bf16x4 pk;
#pragma unroll
  for (int j = 0; j < 4; ++j) pk[j] = f2bf(tile[wv][g4 + j]);
  *(bf16x4*)&xh[(((size_t)n * 16 + ch) * 1156 + (size_t)(h + 1) * 34 + (wv + 1)) * 32 + g4] = pk;
}

// ---- halo zeroing for xh and vh + gsum zeroing ----------------------------
__global__ __launch_bounds__(256) void halo_zero_kernel(
    short* __restrict__ xh, short* __restrict__ vh, float* __restrict__ gsum) {
  short* base = (blockIdx.x & 1) ? vh : xh;
  const int plane = blockIdx.x >> 1;  // 0..511 = n*16+ch
  short* dst = base + (size_t)plane * PCH;
  const int t = threadIdx.x;
  if (t < 132) {
    int row, col;
    if (t < 34)       { row = 0;          col = t; }
    else if (t < 68)  { row = 33;         col = t - 34; }
    else if (t < 100) { row = t - 68 + 1; col = 0; }
    else              { row = t - 100 + 1; col = 33; }
    const bf16x8 z = {0, 0, 0, 0, 0, 0, 0, 0};
    short* q = dst + (size_t)(row * 34 + col) * 32;
#pragma unroll
    for (int j = 0; j < 4; ++j) *(bf16x8*)&q[j * 8] = z;
  }
  if (blockIdx.x == 0 && t >= 192) gsum[t - 192] = 0.f;  // 64 floats
}

// ---- FUSED q/k/v conv3x3 via MFMA implicit shift-GEMM (R17-measured) ------
__global__ __launch_bounds__(256, 3) void conv_qkv_kernel(
    const short* __restrict__ xin, const short* __restrict__ wqkv,
    short* __restrict__ outq, short* __restrict__ outk,
    short* __restrict__ outv) {
  __shared__ __align__(16) short As[3][8192];  // [pos 256][ci 32] bf16, x3
  const int tid  = threadIdx.x;
  const int lane = tid & 63;
  const int l15  = lane & 15, lhi = lane >> 4;
  const int w    = tid >> 6;       // wave 0..3 = co quarter
  const int wbase = tid & 192;

  // 2048 blocks. xcd = bid&7; m = bid>>3 in 0..255:
  //   spt = m&7 (fastest), n = xcd*4 + ((m>>3)&3), co-tile = m>>5 (slowest).
  const int xcd = blockIdx.x & 7;
  const int m   = blockIdx.x >> 3;
  const int co0 = (m >> 5) * 64;
  const int spt = m & 7;
  const int n   = xcd * 4 + ((m >> 3) & 3);
  const int h0  = spt * 4;
  const int sp0 = spt * 128;

  const short* srcA = xin + (size_t)n * (16 * PCH) + (size_t)h0 * (34 * 32);
  // merged B: [t*16+kk][nnG][c3][512]; per-wave base at its nnG quarter
  const short* bbase = wqkv + ((size_t)(co0 >> 4) + w) * 1536 + lane * 8;

  f32x4 acc[3][8];
#pragma unroll
  for (int c = 0; c < 3; ++c)
#pragma unroll
    for (int mf = 0; mf < 8; ++mf)
#pragma unroll
      for (int r = 0; r < 4; ++r) acc[c][mf][r] = 0.f;

#define STAGE_A(kk, buf)                                                      \
  {                                                                           \
    const short* gA = srcA + (size_t)(kk) * PCH;                              \
    _Pragma("unroll") for (int pass = 0; pass < 4; ++pass)                    \
        gload_lds16(gA + (size_t)(pass * 256 + tid) * 8,                      \
                    &As[buf][(pass * 256 + wbase) * 8]);                      \
  }

  STAGE_A(0, 0);
  STAGE_A(1, 1);
  bf16x8 cur[3];
#pragma unroll
  for (int j = 0; j < 3; ++j)  // b(kk=0, t=0): issued AFTER the two stages
    cur[j] = *(const bf16x8*)&bbase[(size_t)j * 512];

  int ab = 0;   // buffer holding stage kk
  int sb = 2;   // buffer to stage kk+2 into
  for (int kk = 0; kk < 16; ++kk) {
    // FIFO oldest-first: newest 7 VM ops = last tap's 3 B reloads +
    // stage(kk+1)'s 4. stage(kk) is ancient -> retired.
    asm volatile("s_waitcnt vmcnt(7)" ::: "memory");
    __builtin_amdgcn_s_barrier();
#pragma unroll
    for (int t = 0; t < 9; ++t) {
      if (t == 1 && kk < 14) STAGE_A(kk + 2, sb);
      const int dy = t / 3, dx = t % 3;
      bf16x8 a[8];
#pragma unroll
      for (int mf = 0; mf < 8; ++mf) {
        const int pb = ((mf >> 1) + dy) * 34 + (mf & 1) * 16 + l15 + dx;
        a[mf] = *(const bf16x8*)&As[ab][pb * 32 + lhi * 8];
      }
      // next tap's B offset (t==8: next kk's tap 0; kk==15 tail reads
      // in-bounds garbage at wqkv[16*49152..], never consumed)
      const int nt  = (t < 8) ? (t + 1) : 0;
      const int nkk = (t < 8) ? kk : kk + 1;
      const size_t bo = (size_t)(nt * 16 + nkk) * 49152;
      const short* brel = &bbase[bo];
#pragma unroll
      for (int c = 0; c < 3; ++c) {
        __builtin_amdgcn_s_setprio(1);
#pragma unroll
        for (int mf = 0; mf < 8; ++mf)
          acc[c][mf] = __builtin_amdgcn_mfma_f32_16x16x32_bf16(
              a[mf], cur[c], acc[c][mf], 0, 0, 0);
        __builtin_amdgcn_s_setprio(0);
        // in-place rotate: one base, imm offsets 0/1024/2048 B
        cur[c] = *(const bf16x8*)&brel[(size_t)c * 512];
      }
    }
    ab = (ab == 2) ? 0 : ab + 1;
    sb = (sb == 2) ? 0 : sb + 1;
  }
#undef STAGE_A

  short* outs[3] = {outq, outk, outv};
#pragma unroll
  for (int c = 0; c < 3; ++c) {
    short* out = outs[c];
#pragma unroll
    for (int mf = 0; mf < 8; ++mf)
#pragma unroll
      for (int r = 0; r < 4; ++r) {
        size_t off = ((size_t)n * kHW + sp0 + mf * 16 + lhi * 4 + r) * kC
                     + co0 + w * 16 + l15;
        out[off] = f2bf(acc[c][mf][r]);
      }
  }
}

// ---- conv_o (128co x 128sp), wave = 32co x 128sp (R16-verified, frozen) ---
__global__ __launch_bounds__(256, 3) void conv_o_kernel(
    const short* __restrict__ xin, const short* __restrict__ wtf,
    const float* __restrict__ xres, float* __restrict__ out) {
  __shared__ __align__(16) short As[3][8192];
  const int tid  = threadIdx.x;
  const int lane = tid & 63;
  const int l15  = lane & 15, lhi = lane >> 4;
  const int w    = tid >> 6;       // wave 0..3 = co quarter (32 co each)
  const int wbase = tid & 192;

  const int xcd = blockIdx.x & 7;
  const int m   = blockIdx.x >> 3;
  const int co0 = (m >> 5) * 128;
  const int spt = m & 7;
  const int n   = xcd * 4 + ((m >> 3) & 3);
  const int h0  = spt * 4;
  const int sp0 = spt * 128;

  const short* srcA = xin + (size_t)n * (16 * PCH) + (size_t)h0 * (34 * 32);
  const short* bptr = wtf + ((size_t)(co0 >> 4) + w * 2) * 512 + lane * 8;

  f32x4 acc[2][8];
#pragma unroll
  for (int nf = 0; nf < 2; ++nf)
#pragma unroll
    for (int mf = 0; mf < 8; ++mf)
#pragma unroll
      for (int r = 0; r < 4; ++r) acc[nf][mf][r] = 0.f;

#define STAGE_A(kk, buf)                                                      \
  {                                                                           \
    const short* gA = srcA + (size_t)(kk) * PCH;                              \
    _Pragma("unroll") for (int pass = 0; pass < 4; ++pass)                    \
        gload_lds16(gA + (size_t)(pass * 256 + tid) * 8,                      \
                    &As[buf][(pass * 256 + wbase) * 8]);                      \
  }

  STAGE_A(0, 0);
  STAGE_A(1, 1);
  bf16x8 cur[2], nxt[2];
#pragma unroll
  for (int j = 0; j < 2; ++j)
    cur[j] = *(const bf16x8*)&bptr[(size_t)j * 512];

  int ab = 0, sb = 2;
  for (int kk = 0; kk < 16; ++kk) {
    asm volatile("s_waitcnt vmcnt(6)" ::: "memory");
    __builtin_amdgcn_s_barrier();
#pragma unroll
    for (int t = 0; t < 9; ++t) {
      {
        const int nt  = (t < 8) ? (t + 1) : 0;
        const int nkk = (t < 8) ? kk : kk + 1;
        const size_t bo = (size_t)(nt * 16 + nkk) * 16384;
#pragma unroll
        for (int j = 0; j < 2; ++j)
          nxt[j] = *(const bf16x8*)&bptr[bo + (size_t)j * 512];
      }
      if (t == 1 && kk < 14) STAGE_A(kk + 2, sb);
      const int dy = t / 3, dx = t % 3;
      bf16x8 a[8];
#pragma unroll
      for (int mf = 0; mf < 8; ++mf) {
        const int pb = ((mf >> 1) + dy) * 34 + (mf & 1) * 16 + l15 + dx;
        a[mf] = *(const bf16x8*)&As[ab][pb * 32 + lhi * 8];
      }
      __builtin_amdgcn_s_setprio(1);
#pragma unroll
      for (int nf = 0; nf < 2; ++nf)
#pragma unroll
        for (int mf = 0; mf < 8; ++mf)
          acc[nf][mf] = __builtin_amdgcn_mfma_f32_16x16x32_bf16(
              a[mf], cur[nf], acc[nf][mf], 0, 0, 0);
      __builtin_amdgcn_s_setprio(0);
#pragma unroll
      for (int j = 0; j < 2; ++j) cur[j] = nxt[j];
    }
    ab = (ab == 2) ? 0 : ab + 1;
    sb = (sb == 2) ? 0 : sb + 1;
  }
#undef STAGE_A

  float* T = (float*)&As[0][0];
#pragma unroll
  for (int nf = 0; nf < 2; ++nf) {
    __syncthreads();
    const int tr = w * 16 + l15;
#pragma unroll
    for (int mf = 0; mf < 8; ++mf)
#pragma unroll
      for (int r = 0; r < 4; ++r)
        T[tr * 129 + mf * 16 + lhi * 4 + r] = acc[nf][mf][r];
    __syncthreads();
#pragma unroll
    for (int it = 0; it < 32; ++it) {
      int idx = it * 256 + tid;
      int trr = idx >> 7, sp = idx & 127;
      int co = co0 + (trr >> 4) * 32 + nf * 16 + (trr & 15);
      size_t off = ((size_t)n * kC + co) * kHW + sp0 + sp;
      out[off] = T[trr * 129 + sp] + xres[off];
    }
  }
}

// ---- MFMA per-pixel attention + fused GN sums, T14 double-buffered --------
__global__ __launch_bounds__(256) void attn_mfma_kernel(
    const short* q, const short* __restrict__ k,
    const short* __restrict__ v, short* virt, float* __restrict__ gsum) {
  __shared__ __align__(16) short Qs[2][32 * 72];
  __shared__ __align__(16) short Ks[2][32 * 72];
  __shared__ __align__(16) float Ps[32 * 36];
  __shared__ __align__(16) short Vt[2][64 * 40];
  const int p    = blockIdx.x;
  const int tid  = threadIdx.x;
  const int lane = tid & 63;
  const int l15  = lane & 15, lhi = lane >> 4;
  const int w    = tid >> 6;       // wave 0..3
  const int iq   = w >> 1, jq = w & 1;  // S quadrant

  f32x4 accS = {0.f, 0.f, 0.f, 0.f};
  const int si = tid >> 3;
  const int sc = (tid & 7) * 8;
  const size_t gstep = ((size_t)si * kHW + p) * kC + sc;
  bf16x8 rq = *(const bf16x8*)&q[gstep];
  bf16x8 rk = *(const bf16x8*)&k[gstep];
  for (int i = 0; i < 8; ++i) {
    const int cb = i & 1;
    *(bf16x8*)&Qs[cb][si * 72 + sc] = rq;
    *(bf16x8*)&Ks[cb][si * 72 + sc] = rk;
    if (i < 7) {  // issue next tile's reg loads; land under this tile's MFMA
      rq = *(const bf16x8*)&q[gstep + (i + 1) * 64];
      rk = *(const bf16x8*)&k[gstep + (i + 1) * 64];
    }
    __syncthreads();
#pragma unroll
    for (int cs = 0; cs < 2; ++cs) {
      bf16x8 aq = *(const bf16x8*)&Qs[cb][(iq * 16 + l15) * 72 + cs * 32 + lhi * 8];
      bf16x8 bk = *(const bf16x8*)&Ks[cb][(jq * 16 + l15) * 72 + cs * 32 + lhi * 8];
      accS = __builtin_amdgcn_mfma_f32_16x16x32_bf16(aq, bk, accS, 0, 0, 0);
    }
  }
  __syncthreads();
  constexpr float scale = 0.044194173824159216f;  // 1/sqrt(512)
#pragma unroll
  for (int r = 0; r < 4; ++r)
    Ps[(iq * 16 + lhi * 4 + r) * 36 + jq * 16 + l15] = accS[r] * scale;
  __syncthreads();

  {
    const int i  = tid >> 3;
    const int j0 = (tid & 7) * 4;
    float a0 = Ps[i * 36 + j0], a1 = Ps[i * 36 + j0 + 1];
    float a2 = Ps[i * 36 + j0 + 2], a3 = Ps[i * 36 + j0 + 3];
    float mx = fmaxf(fmaxf(a0, a1), fmaxf(a2, a3));
    for (int off = 1; off < 8; off <<= 1) mx = fmaxf(mx, __shfl_xor(mx, off));
    float e0 = __expf(a0 - mx), e1 = __expf(a1 - mx);
    float e2 = __expf(a2 - mx), e3 = __expf(a3 - mx);
    float s = e0 + e1 + e2 + e3;
    for (int off = 1; off < 8; off <<= 1) s += __shfl_xor(s, off);
    const float inv = 1.f / s;
    Ps[i * 36 + j0]     = e0 * inv;
    Ps[i * 36 + j0 + 1] = e1 * inv;
    Ps[i * 36 + j0 + 2] = e2 * inv;
    Ps[i * 36 + j0 + 3] = e3 * inv;
  }
  __syncthreads();

  bf16x8 ap[2];
#pragma unroll
  for (int it = 0; it < 2; ++it) {
    const float* pr = &Ps[(it * 16 + l15) * 36 + lhi * 8];
    float4 lo = *(const float4*)pr;
    float4 hi4 = *(const float4*)(pr + 4);
    ap[it][0] = f2bf(lo.x);  ap[it][1] = f2bf(lo.y);
    ap[it][2] = f2bf(lo.z);  ap[it][3] = f2bf(lo.w);
    ap[it][4] = f2bf(hi4.x); ap[it][5] = f2bf(hi4.y);
    ap[it][6] = f2bf(hi4.z); ap[it][7] = f2bf(hi4.w);
  }
  __syncthreads();  // all reads of Ps done before epilogue reuses it

  float gs[8], gq2[8];
#pragma unroll
  for (int idx = 0; idx < 8; ++idx) { gs[idx] = 0.f; gq2[idx] = 0.f; }

  const f32x4 zacc = {0.f, 0.f, 0.f, 0.f};
  const int vj = tid >> 3, vc8 = tid & 7;
  const size_t vstep = ((size_t)vj * kHW + p) * kC + vc8 * 8;
  bf16x8 rv = *(const bf16x8*)&v[vstep];
  for (int i = 0; i < 8; ++i) {
    const int cb = i & 1;
    {
      char* vtb = (char*)&Vt[cb][0];
#pragma unroll
      for (int jj = 0; jj < 8; ++jj) {
        int c = vc8 * 8 + jj;
        int byte = (c * 80 + vj * 2) ^ (((c >> 3) & 7) << 4);
        *(short*)(vtb + byte) = rv[jj];
      }
    }
    if (i < 7) rv = *(const bf16x8*)&v[vstep + (i + 1) * 64];
    __syncthreads();
    {
      const int c0 = i * 64;
      const int c = w * 16 + l15;
      const int byte = (c * 80 + lhi * 16) ^ (((c >> 3) & 7) << 4);
      bf16x8 bv = *(const bf16x8*)((const char*)&Vt[cb][0] + byte);
#pragma unroll
      for (int it = 0; it < 2; ++it) {
        f32x4 o = __builtin_amdgcn_mfma_f32_16x16x32_bf16(ap[it], bv, zacc, 0, 0, 0);
#pragma unroll
        for (int r = 0; r < 4; ++r) {
          short ob = f2bf(o[r]);
          virt[((size_t)(it * 16 + lhi * 4 + r) * kHW + p) * kC + c0 + w * 16 + l15] = ob;
          float fv = bf2f(ob);
          gs[it * 4 + r] += fv;
          gq2[it * 4 + r] = fmaf(fv, fv, gq2[it * 4 + r]);
        }
      }
    }
  }

  // GN partial sums: reduce over the 16 l15-lanes sharing (it,lhi,r)
#pragma unroll
  for (int idx = 0; idx < 8; ++idx)
    for (int off = 1; off < 16; off <<= 1) {
      gs[idx]  += __shfl_xor(gs[idx], off);
      gq2[idx] += __shfl_xor(gq2[idx], off);
    }
  __syncthreads();
  float* SS = Ps;   // [w][32 inst][2] = 256 floats
  if (l15 == 0) {
#pragma unroll
    for (int idx = 0; idx < 8; ++idx) {
      int it = idx >> 2, r = idx & 3;
      int i = it * 16 + lhi * 4 + r;
      SS[(w * 32 + i) * 2]     = gs[idx];
      SS[(w * 32 + i) * 2 + 1] = gq2[idx];
    }
  }
  __syncthreads();
  if (tid < 32) {
    float s = 0.f, q2 = 0.f;
#pragma unroll
    for (int ww = 0; ww < 4; ++ww) {
      s  += SS[(ww * 32 + tid) * 2];
      q2 += SS[(ww * 32 + tid) * 2 + 1];
    }
    atomicAdd(&gsum[tid], s);
    atomicAdd(&gsum[32 + tid], q2);
  }
}

// ---- GN apply + affine + ReLU -> chunked-padded bf16 (stats inline) -------
__global__ __launch_bounds__(256) void gn_apply_kernel(
    const short* __restrict__ virt, const float* __restrict__ gsum,
    const float* __restrict__ gamma, const float* __restrict__ beta,
    short* __restrict__ vh) {
  const size_t g = (size_t)blockIdx.x * 256 + threadIdx.x;
  const int i    = (int)(g >> 16);
  const int rest = (int)(g & 65535);
  const int p    = rest >> 6;
  const int c8g  = rest & 63;
  const int ci   = c8g * 8;
  constexpr float invn = 1.f / ((float)kHW * kC);
  const float mean = gsum[i] * invn;
  const float var  = gsum[32 + i] * invn - mean * mean;
  const float rstd = rsqrtf(var + 1e-5f);
  bf16x8 vv = *(const bf16x8*)&virt[((size_t)i * kHW + p) * kC + ci];
  const float4 ga = ((const float4*)gamma)[c8g * 2];
  const float4 gb = ((const float4*)gamma)[c8g * 2 + 1];
  const float4 ba = ((const float4*)beta)[c8g * 2];
  const float4 bb = ((const float4*)beta)[c8g * 2 + 1];
  const float gv[8] = {ga.x, ga.y, ga.z, ga.w, gb.x, gb.y, gb.z, gb.w};
  const float bv[8] = {ba.x, ba.y, ba.z, ba.w, bb.x, bb.y, bb.z, bb.w};
  bf16x8 o;
#pragma unroll
  for (int jj = 0; jj < 8; ++jj) {
    float f = (bf2f(vv[jj]) - mean) * rstd;
    f = fmaxf(fmaf(f, gv[jj], bv[jj]), 0.f);
    o[jj] = f2bf(f);
  }
  const size_t dst =
      (((size_t)i * 16 + (ci >> 5)) * 1156 + (size_t)((p >> 5) + 1) * 34 + (p & 31) + 1) * 32
      + (ci & 31);
  *(bf16x8*)&vh[dst] = o;
}

}  // namespace

extern "C" void kernel_launch(void* const* d_in, const int* in_sizes, int n_in,
                              void* d_out, int out_size, void* d_ws,
                              size_t ws_size, hipStream_t stream) {
  const float* x     = (const float*)d_in[0];
  const float* w_q   = (const float*)d_in[1];
  const float* w_k   = (const float*)d_in[2];
  const float* w_v   = (const float*)d_in[3];
  const float* w_o   = (const float*)d_in[4];
  const float* gamma = (const float*)d_in[5];
  const float* beta  = (const float*)d_in[6];

  short* ws    = (short*)d_ws;
  short* wqkv  = ws;                       // merged q/k/v weights (3x WTF)
  short* wtf_o = wqkv + 3 * WTF_ELEMS;
  short* xh    = wtf_o + WTF_ELEMS;
  short* vh    = xh + XH_ELEMS;
  short* qb    = vh + XH_ELEMS;
  short* kb    = qb + QKV_ELEMS;
  short* vb    = kb + QKV_ELEMS;
  float* gsum  = (float*)(vb + QKV_ELEMS);  // 64 floats (sum, sumsq)
  short* virt  = qb;  // attn writes per-position after reading q

  halo_zero_kernel<<<1024, 256, 0, stream>>>(xh, vh, gsum);

  wtf_pack_kernel<<<dim3(16, 16, 4), 256, 0, stream>>>(
      w_q, w_k, w_v, w_o, wqkv, wtf_o);

  x2xh_kernel<<<dim3(16, 32, 32), 256, 0, stream>>>(x, xh);

  conv_qkv_kernel<<<2048, 256, 0, stream>>>(xh, wqkv, qb, kb, vb);

  attn_mfma_kernel<<<kHW, 256, 0, stream>>>(qb, kb, vb, virt, gsum);

  gn_apply_kernel<<<(int)(QKV_ELEMS / 8 / 256), 256, 0, stream>>>(
      virt, gsum, gamma, beta, vh);

  conv_o_kernel<<<1024, 256, 0, stream>>>(vh, wtf_o, x, (float*)d_out);
}